// Round 6
// baseline (75.392 us; speedup 1.0000x reference)
//
#include <hip/hip_runtime.h>
#include <math.h>

typedef unsigned int uint;
typedef unsigned long long ull;

__device__ __forceinline__ float lrelu(float z){ return fmaxf(z, 0.5f*z); }
__device__ __forceinline__ float reluf(float z){ return fmaxf(z, 0.f); }
__device__ __forceinline__ float sigm(float z){ return 1.f/(1.f + __expf(-z)); }
__device__ __forceinline__ float tanh_fast(float z){ return 2.f/(1.f + __expf(-2.f*z)) - 1.f; }

// ================= K1: pack (0..511) + LSTM (512..519) + consts (520) =================
// gpk [b][i*2+h] (ull): bit k = adj[b][i][64h+k] > 0        (row-major)
// gpkT[b][j*2+h] (ull): bit k = adj[b][64h+k][j] > 0        (col-major)
// consts: [0]=c1 [1]=c2 [2..9]=P [10..17]=Q [18]=pA [19]=qA [20]=pB [21]=qB
__global__ __launch_bounds__(256) void pack_prep_kernel(
    const int* __restrict__ adj, ull* __restrict__ gpk, ull* __restrict__ gpkT,
    const float* __restrict__ W1, const float* __restrict__ a1,
    const float* __restrict__ W2, const float* __restrict__ a2,
    float* __restrict__ consts,
    const float* __restrict__ ipop,
    const float* __restrict__ wih0, const float* __restrict__ whh0,
    const float* __restrict__ bih0, const float* __restrict__ bhh0,
    const float* __restrict__ wih1, const float* __restrict__ whh1,
    const float* __restrict__ bih1, const float* __restrict__ bhh1,
    float* __restrict__ ip_out)
{
  const int bid = blockIdx.x, t = threadIdx.x;

  if (bid < 512){
    __shared__ int tile[16384];                 // 64 KB: adj[i][j] = tile[i*128+j]
    // ---- phase A: pure stream global -> LDS (register-staged, no exec changes) ----
    const int4* src = (const int4*)(adj + (((long)bid) << 14));
    int4* dst = (int4*)tile;
    #pragma unroll
    for (int r = 0; r < 2; ++r){
      int4 v[8];
      #pragma unroll
      for (int q = 0; q < 8; ++q) v[q] = src[(r*8 + q)*256 + t];
      #pragma unroll
      for (int q = 0; q < 8; ++q) dst[(r*8 + q)*256 + t] = v[q];
    }
    __syncthreads();
    // ---- phase B1: row word. thread t -> i = t>>1, h = t&1; bit k <-> col 64h+k ----
    {
      const int i = t >> 1, h = t & 1;
      const int base = i*128 + 64*h;
      ull w = 0;
      #pragma unroll 8
      for (int kk = 0; kk < 64; ++kk){
        int k = (kk + t) & 63;                  // lane-rotated: 2-way bank alias (free)
        w |= (tile[base + k] > 0) ? (1ull << k) : 0ull;
      }
      gpk[bid*256 + t] = w;                     // t == i*2 + h
    }
    // ---- phase B2: col word. thread t -> j = t&127, h2 = t>>7; bit k <-> row 64h2+k ----
    {
      const int j = t & 127, h2 = t >> 7;
      ull w = 0;
      #pragma unroll 8
      for (int k = 0; k < 64; ++k){
        w |= (tile[(64*h2 + k)*128 + j] > 0) ? (1ull << k) : 0ull;
      }
      gpkT[bid*256 + j*2 + h2] = w;
    }
    return;
  }
  if (bid < 520){
    // ---- LSTM: 8 blocks x 64 threads = 512 sequences ----
    if (t >= 64) return;
    const int b = (bid - 512)*64 + t;
    float wi0[4], wh0[4], bb0[4], wi1[4], wh1[4], bb1[4];
    #pragma unroll
    for (int k = 0; k < 4; ++k){
      wi0[k]=wih0[k]; wh0[k]=whh0[k]; bb0[k]=bih0[k]+bhh0[k];
      wi1[k]=wih1[k]; wh1[k]=whh1[k]; bb1[k]=bih1[k]+bhh1[k];
    }
    float h1=0.f, c1v=0.f, h2=0.f, c2v=0.f;
    for (int tt = 0; tt < 64; ++tt){
      float x = ipop[b*64 + tt];
      float gi = sigm     (__fmaf_rn(x, wi0[0], __fmaf_rn(h1, wh0[0], bb0[0])));
      float gf = sigm     (__fmaf_rn(x, wi0[1], __fmaf_rn(h1, wh0[1], bb0[1])));
      float gg = tanh_fast(__fmaf_rn(x, wi0[2], __fmaf_rn(h1, wh0[2], bb0[2])));
      float go = sigm     (__fmaf_rn(x, wi0[3], __fmaf_rn(h1, wh0[3], bb0[3])));
      c1v = gf*c1v + gi*gg; h1 = go*tanh_fast(c1v);
      float hi2 = sigm     (__fmaf_rn(h1, wi1[0], __fmaf_rn(h2, wh1[0], bb1[0])));
      float hf2 = sigm     (__fmaf_rn(h1, wi1[1], __fmaf_rn(h2, wh1[1], bb1[1])));
      float hg2 = tanh_fast(__fmaf_rn(h1, wi1[2], __fmaf_rn(h2, wh1[2], bb1[2])));
      float ho2 = sigm     (__fmaf_rn(h1, wi1[3], __fmaf_rn(h2, wh1[3], bb1[3])));
      c2v = hf2*c2v + hi2*hg2; h2 = ho2*tanh_fast(c2v);
      ip_out[b*64 + tt] = h2;
    }
    return;
  }
  // ---- consts block ----
  {
    __shared__ float redA[256], redB[256];
    float s1 = 0.f, s2 = 0.f;
    for (int f = t; f < 512; f += 256){ float w = W1[f]; s1 += w*a1[f]; s2 += w*a1[512+f]; }
    redA[t] = s1; redB[t] = s2; __syncthreads();
    for (int st = 128; st > 0; st >>= 1){
      if (t < st){ redA[t] += redA[t+st]; redB[t] += redB[t+st]; }
      __syncthreads();
    }
    if (t == 0){ consts[0] = redA[0]; consts[1] = redB[0]; }
    __syncthreads();
    const int g = t >> 5, seg = t & 31;
    float accP = 0.f, accQ = 0.f;
    for (int k = 0; k < 16; ++k){
      int f = seg*16 + k;
      float w = W1[f];
      float v = w * W2[f*8 + g];
      if (w > 0.f) accP += v; else accQ += v;
    }
    redA[t] = accP; redB[t] = accQ; __syncthreads();
    for (int st = 16; st > 0; st >>= 1){
      if (seg < st){ redA[t] += redA[t+st]; redB[t] += redB[t+st]; }
      __syncthreads();
    }
    if (seg == 0){ consts[2+g] = redA[t]; consts[10+g] = redB[t]; }
    __syncthreads();
    if (t == 0){
      float pA=0.f,qA=0.f,pB=0.f,qB=0.f;
      for (int gg = 0; gg < 8; ++gg){
        pA += consts[2+gg]*a2[gg];   qA += consts[10+gg]*a2[gg];
        pB += consts[2+gg]*a2[8+gg]; qB += consts[10+gg]*a2[8+gg];
      }
      consts[18]=pA; consts[19]=qA; consts[20]=pB; consts[21]=qB;
    }
  }
}

// ================= K2: exp-factorized GAT1+GAT2 + pooling + MHA + MLP head =================
// 256 threads, one batch per block. Inner pass loops have NO exp and NO mask LDS reads.
__global__ __launch_bounds__(256) void gat_head_kernel(
    const ull* __restrict__ gpk, const ull* __restrict__ gpkT,
    const float* __restrict__ feat, const float* __restrict__ timei,
    const float* __restrict__ Weight, const float* __restrict__ Wv,
    const float* __restrict__ consts, const float* __restrict__ ip,
    const float* __restrict__ mha_in_w, const float* __restrict__ mha_in_b,
    const float* __restrict__ mha_out_w, const float* __restrict__ mha_out_b,
    const float* __restrict__ fl1_w, const float* __restrict__ fl1_b,
    const float* __restrict__ fl2_w, const float* __restrict__ fl2_b,
    const float* __restrict__ fl3_w, const float* __restrict__ fl3_b,
    float* __restrict__ out)
{
  const int b = blockIdx.x, t = threadIdx.x;
  const int lane = t & 127, h = t >> 7;        // h in {0,1}: 64-chunk of the other axis

  __shared__ float  xs[128], tim[128], hm[128], eAs[128], thr1[128];
  __shared__ float2 f2a[128];                  // {E1_i, Eh_i}
  __shared__ float2 red2[2][128];              // pass partials / V-pair staging / fl1 partials
  __shared__ float4 q4[128];                   // {G1,G2,thr,-} then {Gp1,Gp2,Gn1,Gn2}
  __shared__ float4 pool4[2][128];             // row2 partials / pooling partials
  __shared__ float2 kv[192];
  __shared__ float  hq[192], h2s[192];
  __shared__ float  sred[8];

  const float c1 = consts[0], c2 = consts[1];
  const float pA = consts[18], qA = consts[19], pB = consts[20], qB = consts[21];

  // ---- phase 0: loads (masks into registers) ----
  float ipreg = 0.f;
  if (t < 128){ xs[t] = feat[b*128 + t]; tim[t] = timei[b*128 + t]; }
  if (t >= 192) ipreg = ip[b*64 + (t - 192)];
  const ull rowm = gpk [b*256 + lane*2 + h];   // bit k = adj[lane][64h+k]
  const ull colm = gpkT[b*256 + lane*2 + h];   // bit k = adj[64h+k][lane]
  __syncthreads();
  if (t < 64){
    float mx = fmaxf(xs[t], xs[t+64]);
    float mn = fminf(xs[t], xs[t+64]);
    #pragma unroll
    for (int off = 32; off; off >>= 1){
      mx = fmaxf(mx, __shfl_xor(mx, off));
      mn = fminf(mn, __shfl_xor(mn, off));
    }
    if (t == 0){ sred[0] = mx; sred[1] = mn; }
  }
  __syncthreads();

  // ---- phase 0b: per-node factors for GAT1 ----
  float myE1=0.f, myEh=0.f, myA=0.f, myB=0.f, mythr=0.f, myx=0.f;
  {
    const float rmax = (c1 >= 0.f) ? c1*sred[0] : c1*sred[1];
    if (t < 128){
      myx = xs[t];
      float r  = c1*myx;
      float cj = c2*myx;
      float cb = lrelu(rmax + cj);
      myE1  = __expf(r - rmax);
      myEh  = __expf(0.5f*(r - rmax));
      myA   = __expf(rmax + cj - cb);
      myB   = __expf(0.5f*(rmax + cj) - cb);
      mythr = __expf(-cj - rmax);
      f2a[t] = make_float2(myE1, myEh);
      thr1[t] = mythr;
    }
  }
  __syncthreads();

  // ---- GAT1 col pass: S1,S2 per column ----
  {
    const float thrj = thr1[lane];
    float s1 = 0.f, s2 = 0.f;
    #pragma unroll 8
    for (int k = 0; k < 64; ++k){
      float2 E = f2a[64*h + k];                // broadcast
      bool m = ((colm >> k) & 1ull);
      bool cond = (E.x >= thrj);
      s1 += (m &&  cond) ? E.x : 0.f;
      s2 += (m && !cond) ? E.y : 0.f;
    }
    red2[h][lane] = make_float2(s1, s2);
  }
  __syncthreads();
  // ---- combine: cr, per-column G table ----
  if (t < 128){
    float2 a = red2[0][t], bb = red2[1][t];
    float den = __fmaf_rn(myA, a.x + bb.x, myB*(a.y + bb.y));
    float cr = 1.f/den;
    q4[t] = make_float4(myA*cr*myx, myB*cr*myx, mythr, 0.f);
  }
  __syncthreads();
  // ---- GAT1 row pass: u_i = E1_i*T1 + Eh_i*T2 ----
  {
    const float2 Eo = f2a[lane];
    float t1 = 0.f, t2 = 0.f;
    #pragma unroll 8
    for (int k = 0; k < 64; ++k){
      float4 G = q4[64*h + k];                 // broadcast
      bool m = ((rowm >> k) & 1ull);
      bool cond = (Eo.x >= G.z);
      t1 += (m &&  cond) ? G.x : 0.f;
      t2 += (m && !cond) ? G.y : 0.f;
    }
    red2[h][lane] = make_float2(t1, t2);
  }
  __syncthreads();
  // ---- u, eA, eB; eA max ----
  float u = 0.f, eBv = 0.f, eAv = 0.f;
  if (t < 128){
    float2 a = red2[0][t], bb = red2[1][t];
    u = __fmaf_rn(myE1, a.x + bb.x, myEh*(a.y + bb.y));
    eAv = (u >= 0.f ? pA : qA)*u;
    eBv = (u >= 0.f ? pB : qB)*u;
    eAs[t] = eAv;
  }
  __syncthreads();
  if (t < 64){
    float mx = fmaxf(eAs[t], eAs[t+64]);
    #pragma unroll
    for (int off = 32; off; off >>= 1) mx = fmaxf(mx, __shfl_xor(mx, off));
    if (t == 0) sred[2] = mx;
  }
  __syncthreads();
  // ---- per-node factors for GAT2 ----
  float myE1b=0.f, myEhb=0.f, myA2=0.f, myB2=0.f;
  {
    const float eAmax = sred[2];
    if (t < 128){
      float cb = lrelu(eAmax + eBv);
      myE1b = __expf(eAv - eAmax);
      myEhb = __expf(0.5f*(eAv - eAmax));
      myA2  = __expf(eAmax + eBv - cb);
      myB2  = __expf(0.5f*(eAmax + eBv) - cb);
      float th = __expf(-eBv - eAmax);
      f2a[t] = make_float2(myE1b, myEhb);
      thr1[t] = th;
    }
  }
  __syncthreads();
  // ---- GAT2 col pass ----
  {
    const float thrj = thr1[lane];
    float s1 = 0.f, s2 = 0.f;
    #pragma unroll 8
    for (int k = 0; k < 64; ++k){
      float2 E = f2a[64*h + k];
      bool m = ((colm >> k) & 1ull);
      bool cond = (E.x >= thrj);
      s1 += (m &&  cond) ? E.x : 0.f;
      s2 += (m && !cond) ? E.y : 0.f;
    }
    red2[h][lane] = make_float2(s1, s2);
  }
  __syncthreads();
  if (t < 128){
    float2 a = red2[0][t], bb = red2[1][t];
    float den = __fmaf_rn(myA2, a.x + bb.x, myB2*(a.y + bb.y));
    float cr = 1.f/den;
    float up = fmaxf(u, 0.f), un = fminf(u, 0.f);
    q4[t] = make_float4(myA2*cr*up, myB2*cr*up, myA2*cr*un, myB2*cr*un);
  }
  __syncthreads();
  // ---- GAT2 row pass: sp/sn (4 accumulators) ----
  {
    const float2 Eo = f2a[lane];
    float sp1=0.f, sp2=0.f, sn1=0.f, sn2=0.f;
    #pragma unroll 8
    for (int k = 0; k < 64; ++k){
      int j = 64*h + k;
      float4 G = q4[j];
      float thj = thr1[j];
      bool m = ((rowm >> k) & 1ull);
      bool cond = (Eo.x >= thj);
      sp1 += (m &&  cond) ? G.x : 0.f;
      sp2 += (m && !cond) ? G.y : 0.f;
      sn1 += (m &&  cond) ? G.z : 0.f;
      sn2 += (m && !cond) ? G.w : 0.f;
    }
    pool4[h][lane] = make_float4(sp1, sp2, sn1, sn2);
  }
  __syncthreads();
  if (t < 128){
    float4 a = pool4[0][t], bb = pool4[1][t];
    float sp = __fmaf_rn(myE1b, a.x + bb.x, myEhb*(a.y + bb.y));
    float sn = __fmaf_rn(myE1b, a.z + bb.z, myEhb*(a.w + bb.w));
    float acc = 0.f;
    #pragma unroll
    for (int g = 0; g < 8; ++g) acc += reluf(__fmaf_rn(sp, consts[2+g], sn*consts[10+g]));
    hm[t] = 0.125f*acc;
  }
  __syncthreads();

  // ---- attention pooling over Weight/Wv (global, L2-resident) ----
  {
    const int n = lane;
    float a0=0.f, a1v=0.f, v0=0.f, v1=0.f;
    const int m0 = h*64;
    #pragma unroll 4
    for (int k = 0; k < 64; ++k){
      int m = m0 + k;
      float hmv = hm[m], tv = tim[m];
      float wg = Weight[(m<<7) + n], wvv = Wv[(m<<7) + n];
      a0 = __fmaf_rn(hmv, wg, a0); a1v = __fmaf_rn(tv, wg, a1v);
      v0 = __fmaf_rn(hmv, wvv, v0); v1 = __fmaf_rn(tv, wvv, v1);
    }
    pool4[h][n] = make_float4(a0, a1v, v0, v1);
  }
  __syncthreads();
  float att0 = 0.f, att1 = 0.f, rsv = 0.f;
  if (t < 128){
    float4 a = pool4[0][t], bb = pool4[1][t];
    float A0 = a.x + bb.x, A1 = a.y + bb.y;
    red2[0][t] = make_float2(a.z + bb.z, a.w + bb.w);   // {V0, V1}
    float mx = fmaxf(A0, A1);
    att0 = __expf(A0 - mx); att1 = __expf(A1 - mx);
    rsv = 1.f/(att0 + att1);
  }
  __syncthreads();
  if (t < 128){
    float r0, r1;
    if (t < 64){ r0 = red2[0][2*t].x;     r1 = red2[0][2*t+1].x; }
    else       { r0 = red2[0][2*t-128].y; r1 = red2[0][2*t-127].y; }
    hq[t] = (reluf(r0)*att0 + reluf(r1)*att1)*rsv;
  }
  if (t >= 192) hq[128 + (t - 192)] = ipreg;
  __syncthreads();

  // ---- MHA (dim-1) + residual ----
  const float wq = mha_in_w[0], wk = mha_in_w[1], wv = mha_in_w[2];
  const float bq = mha_in_b[0], bk = mha_in_b[1], bv = mha_in_b[2];
  const float wo = mha_out_w[0], bo = mha_out_b[0];
  if (t < 192){
    float hv_ = hq[t];
    kv[t] = make_float2(__fmaf_rn(hv_, wk, bk), __fmaf_rn(hv_, wv, bv));
  }
  __syncthreads();
  if (t < 64){
    float k0 = kv[t].x, k1 = kv[t+64].x, k2 = kv[t+128].x;
    float mx = fmaxf(fmaxf(k0, k1), k2);
    float mn = fminf(fminf(k0, k1), k2);
    #pragma unroll
    for (int off = 32; off; off >>= 1){
      mx = fmaxf(mx, __shfl_xor(mx, off));
      mn = fminf(mn, __shfl_xor(mn, off));
    }
    if (t == 0){ sred[3] = mx; sred[4] = mn; }
  }
  __syncthreads();
  if (t < 192){
    float hv_ = hq[t];
    float qi = __fmaf_rn(hv_, wq, bq);
    float mx = (qi >= 0.f) ? qi*sred[3] : qi*sred[4];
    float den = 0.f, num = 0.f;
    #pragma unroll 8
    for (int j = 0; j < 192; ++j){
      float2 K = kv[j];
      float e = __expf(__fmaf_rn(qi, K.x, -mx));
      den += e; num = __fmaf_rn(e, K.y, num);
    }
    h2s[t] = __fmaf_rn(num/den, wo, bo) + hv_;
  }
  __syncthreads();
  // ---- fl1: 192 -> 128, relu (2-way split over j) ----
  {
    const int n = t & 127;
    float acc = 0.f;
    const int i0 = h*96;
    #pragma unroll 8
    for (int k = 0; k < 96; ++k){
      int i = i0 + k;
      acc = __fmaf_rn(h2s[i], fl1_w[i*128 + n], acc);
    }
    red2[h][n].x = acc;
  }
  __syncthreads();
  if (t < 128) thr1[t] = reluf(red2[0][t].x + red2[1][t].x + fl1_b[t]);
  __syncthreads();
  // ---- fl2: 128 -> 32, tanh (4-way split) ----
  if (t < 128){
    const int n = t & 31, seg = t >> 5;
    float p = 0.f;
    #pragma unroll 8
    for (int k = 0; k < 32; ++k){
      int i = seg*32 + k;
      p = __fmaf_rn(thr1[i], fl2_w[i*32 + n], p);
    }
    eAs[t] = p;
  }
  __syncthreads();
  if (t < 32) hm[t] = tanh_fast(eAs[t] + eAs[t+32] + eAs[t+64] + eAs[t+96] + fl2_b[t]);
  __syncthreads();
  // ---- fl3: 32 -> 1, relu ----
  if (t < 64){
    float p = (t < 32) ? hm[t]*fl3_w[t] : 0.f;
    #pragma unroll
    for (int off = 32; off; off >>= 1) p += __shfl_xor(p, off);
    if (t == 0) out[b] = reluf(p + fl3_b[0]);
  }
}

extern "C" void kernel_launch(void* const* d_in, const int* in_sizes, int n_in,
                              void* d_out, int out_size, void* d_ws, size_t ws_size,
                              hipStream_t stream) {
  const int*   adj    = (const int*)  d_in[0];
  const float* feat   = (const float*)d_in[1];
  const float* timei  = (const float*)d_in[2];
  const float* ipop   = (const float*)d_in[3];
  const float* W1     = (const float*)d_in[4];
  const float* a1     = (const float*)d_in[5];
  const float* W2     = (const float*)d_in[6];
  const float* a2     = (const float*)d_in[7];
  const float* Weight = (const float*)d_in[8];
  const float* Wv     = (const float*)d_in[9];
  const float* wih0   = (const float*)d_in[10];
  const float* whh0   = (const float*)d_in[11];
  const float* bih0   = (const float*)d_in[12];
  const float* bhh0   = (const float*)d_in[13];
  const float* wih1   = (const float*)d_in[14];
  const float* whh1   = (const float*)d_in[15];
  const float* bih1   = (const float*)d_in[16];
  const float* bhh1   = (const float*)d_in[17];
  const float* mha_in_w  = (const float*)d_in[18];
  const float* mha_in_b  = (const float*)d_in[19];
  const float* mha_out_w = (const float*)d_in[20];
  const float* mha_out_b = (const float*)d_in[21];
  const float* fl1_w = (const float*)d_in[22];
  const float* fl1_b = (const float*)d_in[23];
  const float* fl2_w = (const float*)d_in[24];
  const float* fl2_b = (const float*)d_in[25];
  const float* fl3_w = (const float*)d_in[26];
  const float* fl3_b = (const float*)d_in[27];

  ull*   gpk    = (ull*)d_ws;                 // 512*256 ull = 1 MB
  ull*   gpkT   = gpk + 131072;               // 1 MB
  float* consts = (float*)(gpkT + 131072);    // 32 floats
  float* ip     = consts + 32;                // 512*64 floats

  pack_prep_kernel<<<521, 256, 0, stream>>>(adj, gpk, gpkT, W1, a1, W2, a2, consts,
                                            ipop, wih0, whh0, bih0, bhh0,
                                            wih1, whh1, bih1, bhh1, ip);
  gat_head_kernel<<<512, 256, 0, stream>>>(gpk, gpkT, feat, timei, Weight, Wv, consts, ip,
                                           mha_in_w, mha_in_b, mha_out_w, mha_out_b,
                                           fl1_w, fl1_b, fl2_w, fl2_b, fl3_w, fl3_b,
                                           (float*)d_out);
}

// Round 7
// 64.677 us; speedup vs baseline: 1.1657x; 1.1657x over previous
//
#include <hip/hip_runtime.h>
#include <math.h>

typedef unsigned int uint;
typedef unsigned long long ull;

__device__ __forceinline__ float lrelu(float z){ return fmaxf(z, 0.5f*z); }
__device__ __forceinline__ float reluf(float z){ return fmaxf(z, 0.f); }
__device__ __forceinline__ float sigm(float z){ return 1.f/(1.f + __expf(-z)); }
__device__ __forceinline__ float tanh_fast(float z){ return 2.f/(1.f + __expf(-2.f*z)) - 1.f; }

// ================= K1: pack (0..511) + LSTM (512..519) + consts (520) =================
// gpk [b][i*2+h] (ull): bit k = adj[b][i][64h+k] > 0        (row-major)
// gpkT[b][j*2+h] (ull): bit k = adj[b][64h+k][j] > 0        (col-major)
// consts: [0]=c1 [1]=c2 [2..9]=P [10..17]=Q [18]=pA [19]=qA [20]=pB [21]=qB
__global__ __launch_bounds__(256) void pack_prep_kernel(
    const int* __restrict__ adj, ull* __restrict__ gpk, ull* __restrict__ gpkT,
    const float* __restrict__ W1, const float* __restrict__ a1,
    const float* __restrict__ W2, const float* __restrict__ a2,
    float* __restrict__ consts,
    const float* __restrict__ ipop,
    const float* __restrict__ wih0, const float* __restrict__ whh0,
    const float* __restrict__ bih0, const float* __restrict__ bhh0,
    const float* __restrict__ wih1, const float* __restrict__ whh1,
    const float* __restrict__ bih1, const float* __restrict__ bhh1,
    float* __restrict__ ip_out)
{
  const int bid = blockIdx.x, t = threadIdx.x;

  if (bid < 512){
    // ---- ballot pack: word W = w*64+ln lives in lane ln of wave w ----
    // addr(W, lane k) = base + W*64 + k = adj[i][64h+k] with W = 2i+h.
    __shared__ ull rowW[256];
    const int w = t >> 6, ln = t & 63;
    const int* abase = adj + (((long)bid) << 14) + w*4096 + ln;
    ull myword = 0;
    #pragma unroll
    for (int blk = 0; blk < 8; ++blk){
      int v[8];
      #pragma unroll
      for (int q = 0; q < 8; ++q) v[q] = abase[(blk*8 + q)*64];   // coalesced, independent
      #pragma unroll
      for (int q = 0; q < 8; ++q){
        ull m = __ballot(v[q] > 0);
        const int it = blk*8 + q;
        myword = (ln == it) ? m : myword;     // cndmask: no exec-mask change
      }
    }
    rowW[t] = myword;
    gpk[bid*256 + t] = myword;
    __syncthreads();
    // ---- col words from LDS (all reads are wave-broadcast: free) ----
    const int j = t & 127, h2 = t >> 7;
    const int wsel = j >> 6, bsel = j & 63;
    ull outw = 0;
    #pragma unroll 8
    for (int k = 0; k < 64; ++k){
      outw |= ((rowW[(64*h2 + k)*2 + wsel] >> bsel) & 1ull) << k;
    }
    gpkT[bid*256 + j*2 + h2] = outw;
    return;
  }
  if (bid < 520){
    // ---- LSTM: 8 blocks x 64 threads = 512 sequences; loads hoisted off the chain ----
    if (t >= 64) return;
    const int b = (bid - 512)*64 + t;
    float wi0[4], wh0[4], bb0[4], wi1[4], wh1[4], bb1[4];
    #pragma unroll
    for (int k = 0; k < 4; ++k){
      wi0[k]=wih0[k]; wh0[k]=whh0[k]; bb0[k]=bih0[k]+bhh0[k];
      wi1[k]=wih1[k]; wh1[k]=whh1[k]; bb1[k]=bih1[k]+bhh1[k];
    }
    const float4* xsrc = (const float4*)(ipop + b*64);
    float4* hdst = (float4*)(ip_out + b*64);
    float4 xv = xsrc[0];
    float h1=0.f, c1v=0.f, h2=0.f, c2v=0.f;
    #pragma unroll
    for (int q = 0; q < 16; ++q){
      const float4 xc = xv;
      if (q < 15) xv = xsrc[q+1];            // prefetch next chunk under the chain
      float hout[4];
      #pragma unroll
      for (int s = 0; s < 4; ++s){
        const float x = (s==0) ? xc.x : (s==1) ? xc.y : (s==2) ? xc.z : xc.w;
        float gi = sigm     (__fmaf_rn(x, wi0[0], __fmaf_rn(h1, wh0[0], bb0[0])));
        float gf = sigm     (__fmaf_rn(x, wi0[1], __fmaf_rn(h1, wh0[1], bb0[1])));
        float gg = tanh_fast(__fmaf_rn(x, wi0[2], __fmaf_rn(h1, wh0[2], bb0[2])));
        float go = sigm     (__fmaf_rn(x, wi0[3], __fmaf_rn(h1, wh0[3], bb0[3])));
        c1v = gf*c1v + gi*gg; h1 = go*tanh_fast(c1v);
        float hi2 = sigm     (__fmaf_rn(h1, wi1[0], __fmaf_rn(h2, wh1[0], bb1[0])));
        float hf2 = sigm     (__fmaf_rn(h1, wi1[1], __fmaf_rn(h2, wh1[1], bb1[1])));
        float hg2 = tanh_fast(__fmaf_rn(h1, wi1[2], __fmaf_rn(h2, wh1[2], bb1[2])));
        float ho2 = sigm     (__fmaf_rn(h1, wi1[3], __fmaf_rn(h2, wh1[3], bb1[3])));
        c2v = hf2*c2v + hi2*hg2; h2 = ho2*tanh_fast(c2v);
        hout[s] = h2;
      }
      hdst[q] = make_float4(hout[0], hout[1], hout[2], hout[3]);
    }
    return;
  }
  // ---- consts block ----
  {
    __shared__ float redA[256], redB[256];
    float s1 = 0.f, s2 = 0.f;
    for (int f = t; f < 512; f += 256){ float w = W1[f]; s1 += w*a1[f]; s2 += w*a1[512+f]; }
    redA[t] = s1; redB[t] = s2; __syncthreads();
    for (int st = 128; st > 0; st >>= 1){
      if (t < st){ redA[t] += redA[t+st]; redB[t] += redB[t+st]; }
      __syncthreads();
    }
    if (t == 0){ consts[0] = redA[0]; consts[1] = redB[0]; }
    __syncthreads();
    const int g = t >> 5, seg = t & 31;
    float accP = 0.f, accQ = 0.f;
    for (int k = 0; k < 16; ++k){
      int f = seg*16 + k;
      float w = W1[f];
      float v = w * W2[f*8 + g];
      if (w > 0.f) accP += v; else accQ += v;
    }
    redA[t] = accP; redB[t] = accQ; __syncthreads();
    for (int st = 16; st > 0; st >>= 1){
      if (seg < st){ redA[t] += redA[t+st]; redB[t] += redB[t+st]; }
      __syncthreads();
    }
    if (seg == 0){ consts[2+g] = redA[t]; consts[10+g] = redB[t]; }
    __syncthreads();
    if (t == 0){
      float pA=0.f,qA=0.f,pB=0.f,qB=0.f;
      for (int gg = 0; gg < 8; ++gg){
        pA += consts[2+gg]*a2[gg];   qA += consts[10+gg]*a2[gg];
        pB += consts[2+gg]*a2[8+gg]; qB += consts[10+gg]*a2[8+gg];
      }
      consts[18]=pA; consts[19]=qA; consts[20]=pB; consts[21]=qB;
    }
  }
}

// ================= K2: exp-factorized GAT1+GAT2 + pooling + MHA + MLP head =================
// 256 threads, one batch per block. Inner pass loops have NO exp and NO mask LDS reads.
__global__ __launch_bounds__(256) void gat_head_kernel(
    const ull* __restrict__ gpk, const ull* __restrict__ gpkT,
    const float* __restrict__ feat, const float* __restrict__ timei,
    const float* __restrict__ Weight, const float* __restrict__ Wv,
    const float* __restrict__ consts, const float* __restrict__ ip,
    const float* __restrict__ mha_in_w, const float* __restrict__ mha_in_b,
    const float* __restrict__ mha_out_w, const float* __restrict__ mha_out_b,
    const float* __restrict__ fl1_w, const float* __restrict__ fl1_b,
    const float* __restrict__ fl2_w, const float* __restrict__ fl2_b,
    const float* __restrict__ fl3_w, const float* __restrict__ fl3_b,
    float* __restrict__ out)
{
  const int b = blockIdx.x, t = threadIdx.x;
  const int lane = t & 127, h = t >> 7;        // h in {0,1}: 64-chunk of the other axis

  __shared__ float  xs[128], tim[128], hm[128], eAs[128], thr1[128];
  __shared__ float2 f2a[128];                  // {E1_i, Eh_i}
  __shared__ float2 red2[2][128];              // pass partials / V-pair staging / fl1 partials
  __shared__ float4 q4[128];                   // {G1,G2,thr,-} then {Gp1,Gp2,Gn1,Gn2}
  __shared__ float4 pool4[2][128];             // row2 partials / pooling partials
  __shared__ float2 kv[192];
  __shared__ float  hq[192], h2s[192];
  __shared__ float  sred[8];

  const float c1 = consts[0], c2 = consts[1];
  const float pA = consts[18], qA = consts[19], pB = consts[20], qB = consts[21];

  // ---- phase 0: loads (masks into registers) ----
  float ipreg = 0.f;
  if (t < 128){ xs[t] = feat[b*128 + t]; tim[t] = timei[b*128 + t]; }
  if (t >= 192) ipreg = ip[b*64 + (t - 192)];
  const ull rowm = gpk [b*256 + lane*2 + h];   // bit k = adj[lane][64h+k]
  const ull colm = gpkT[b*256 + lane*2 + h];   // bit k = adj[64h+k][lane]
  __syncthreads();
  if (t < 64){
    float mx = fmaxf(xs[t], xs[t+64]);
    float mn = fminf(xs[t], xs[t+64]);
    #pragma unroll
    for (int off = 32; off; off >>= 1){
      mx = fmaxf(mx, __shfl_xor(mx, off));
      mn = fminf(mn, __shfl_xor(mn, off));
    }
    if (t == 0){ sred[0] = mx; sred[1] = mn; }
  }
  __syncthreads();

  // ---- phase 0b: per-node factors for GAT1 ----
  float myE1=0.f, myEh=0.f, myA=0.f, myB=0.f, mythr=0.f, myx=0.f;
  {
    const float rmax = (c1 >= 0.f) ? c1*sred[0] : c1*sred[1];
    if (t < 128){
      myx = xs[t];
      float r  = c1*myx;
      float cj = c2*myx;
      float cb = lrelu(rmax + cj);
      myE1  = __expf(r - rmax);
      myEh  = __expf(0.5f*(r - rmax));
      myA   = __expf(rmax + cj - cb);
      myB   = __expf(0.5f*(rmax + cj) - cb);
      mythr = __expf(-cj - rmax);
      f2a[t] = make_float2(myE1, myEh);
      thr1[t] = mythr;
    }
  }
  __syncthreads();

  // ---- GAT1 col pass: S1,S2 per column ----
  {
    const float thrj = thr1[lane];
    float s1 = 0.f, s2 = 0.f;
    #pragma unroll 8
    for (int k = 0; k < 64; ++k){
      float2 E = f2a[64*h + k];                // broadcast
      bool m = ((colm >> k) & 1ull);
      bool cond = (E.x >= thrj);
      s1 += (m &&  cond) ? E.x : 0.f;
      s2 += (m && !cond) ? E.y : 0.f;
    }
    red2[h][lane] = make_float2(s1, s2);
  }
  __syncthreads();
  // ---- combine: cr, per-column G table ----
  if (t < 128){
    float2 a = red2[0][t], bb = red2[1][t];
    float den = __fmaf_rn(myA, a.x + bb.x, myB*(a.y + bb.y));
    float cr = 1.f/den;
    q4[t] = make_float4(myA*cr*myx, myB*cr*myx, mythr, 0.f);
  }
  __syncthreads();
  // ---- GAT1 row pass: u_i = E1_i*T1 + Eh_i*T2 ----
  {
    const float2 Eo = f2a[lane];
    float t1 = 0.f, t2 = 0.f;
    #pragma unroll 8
    for (int k = 0; k < 64; ++k){
      float4 G = q4[64*h + k];                 // broadcast
      bool m = ((rowm >> k) & 1ull);
      bool cond = (Eo.x >= G.z);
      t1 += (m &&  cond) ? G.x : 0.f;
      t2 += (m && !cond) ? G.y : 0.f;
    }
    red2[h][lane] = make_float2(t1, t2);
  }
  __syncthreads();
  // ---- u, eA, eB; eA max ----
  float u = 0.f, eBv = 0.f, eAv = 0.f;
  if (t < 128){
    float2 a = red2[0][t], bb = red2[1][t];
    u = __fmaf_rn(myE1, a.x + bb.x, myEh*(a.y + bb.y));
    eAv = (u >= 0.f ? pA : qA)*u;
    eBv = (u >= 0.f ? pB : qB)*u;
    eAs[t] = eAv;
  }
  __syncthreads();
  if (t < 64){
    float mx = fmaxf(eAs[t], eAs[t+64]);
    #pragma unroll
    for (int off = 32; off; off >>= 1) mx = fmaxf(mx, __shfl_xor(mx, off));
    if (t == 0) sred[2] = mx;
  }
  __syncthreads();
  // ---- per-node factors for GAT2 ----
  float myE1b=0.f, myEhb=0.f, myA2=0.f, myB2=0.f;
  {
    const float eAmax = sred[2];
    if (t < 128){
      float cb = lrelu(eAmax + eBv);
      myE1b = __expf(eAv - eAmax);
      myEhb = __expf(0.5f*(eAv - eAmax));
      myA2  = __expf(eAmax + eBv - cb);
      myB2  = __expf(0.5f*(eAmax + eBv) - cb);
      float th = __expf(-eBv - eAmax);
      f2a[t] = make_float2(myE1b, myEhb);
      thr1[t] = th;
    }
  }
  __syncthreads();
  // ---- GAT2 col pass ----
  {
    const float thrj = thr1[lane];
    float s1 = 0.f, s2 = 0.f;
    #pragma unroll 8
    for (int k = 0; k < 64; ++k){
      float2 E = f2a[64*h + k];
      bool m = ((colm >> k) & 1ull);
      bool cond = (E.x >= thrj);
      s1 += (m &&  cond) ? E.x : 0.f;
      s2 += (m && !cond) ? E.y : 0.f;
    }
    red2[h][lane] = make_float2(s1, s2);
  }
  __syncthreads();
  if (t < 128){
    float2 a = red2[0][t], bb = red2[1][t];
    float den = __fmaf_rn(myA2, a.x + bb.x, myB2*(a.y + bb.y));
    float cr = 1.f/den;
    float up = fmaxf(u, 0.f), un = fminf(u, 0.f);
    q4[t] = make_float4(myA2*cr*up, myB2*cr*up, myA2*cr*un, myB2*cr*un);
  }
  __syncthreads();
  // ---- GAT2 row pass: sp/sn (4 accumulators) ----
  {
    const float2 Eo = f2a[lane];
    float sp1=0.f, sp2=0.f, sn1=0.f, sn2=0.f;
    #pragma unroll 8
    for (int k = 0; k < 64; ++k){
      int j = 64*h + k;
      float4 G = q4[j];
      float thj = thr1[j];
      bool m = ((rowm >> k) & 1ull);
      bool cond = (Eo.x >= thj);
      sp1 += (m &&  cond) ? G.x : 0.f;
      sp2 += (m && !cond) ? G.y : 0.f;
      sn1 += (m &&  cond) ? G.z : 0.f;
      sn2 += (m && !cond) ? G.w : 0.f;
    }
    pool4[h][lane] = make_float4(sp1, sp2, sn1, sn2);
  }
  __syncthreads();
  if (t < 128){
    float4 a = pool4[0][t], bb = pool4[1][t];
    float sp = __fmaf_rn(myE1b, a.x + bb.x, myEhb*(a.y + bb.y));
    float sn = __fmaf_rn(myE1b, a.z + bb.z, myEhb*(a.w + bb.w));
    float acc = 0.f;
    #pragma unroll
    for (int g = 0; g < 8; ++g) acc += reluf(__fmaf_rn(sp, consts[2+g], sn*consts[10+g]));
    hm[t] = 0.125f*acc;
  }
  __syncthreads();

  // ---- attention pooling over Weight/Wv (global, L2-resident) ----
  {
    const int n = lane;
    float a0=0.f, a1v=0.f, v0=0.f, v1=0.f;
    const int m0 = h*64;
    #pragma unroll 4
    for (int k = 0; k < 64; ++k){
      int m = m0 + k;
      float hmv = hm[m], tv = tim[m];
      float wg = Weight[(m<<7) + n], wvv = Wv[(m<<7) + n];
      a0 = __fmaf_rn(hmv, wg, a0); a1v = __fmaf_rn(tv, wg, a1v);
      v0 = __fmaf_rn(hmv, wvv, v0); v1 = __fmaf_rn(tv, wvv, v1);
    }
    pool4[h][n] = make_float4(a0, a1v, v0, v1);
  }
  __syncthreads();
  float att0 = 0.f, att1 = 0.f, rsv = 0.f;
  if (t < 128){
    float4 a = pool4[0][t], bb = pool4[1][t];
    float A0 = a.x + bb.x, A1 = a.y + bb.y;
    red2[0][t] = make_float2(a.z + bb.z, a.w + bb.w);   // {V0, V1}
    float mx = fmaxf(A0, A1);
    att0 = __expf(A0 - mx); att1 = __expf(A1 - mx);
    rsv = 1.f/(att0 + att1);
  }
  __syncthreads();
  if (t < 128){
    float r0, r1;
    if (t < 64){ r0 = red2[0][2*t].x;     r1 = red2[0][2*t+1].x; }
    else       { r0 = red2[0][2*t-128].y; r1 = red2[0][2*t-127].y; }
    hq[t] = (reluf(r0)*att0 + reluf(r1)*att1)*rsv;
  }
  if (t >= 192) hq[128 + (t - 192)] = ipreg;
  __syncthreads();

  // ---- MHA (dim-1) + residual ----
  const float wq = mha_in_w[0], wk = mha_in_w[1], wv = mha_in_w[2];
  const float bq = mha_in_b[0], bk = mha_in_b[1], bv = mha_in_b[2];
  const float wo = mha_out_w[0], bo = mha_out_b[0];
  if (t < 192){
    float hv_ = hq[t];
    kv[t] = make_float2(__fmaf_rn(hv_, wk, bk), __fmaf_rn(hv_, wv, bv));
  }
  __syncthreads();
  if (t < 64){
    float k0 = kv[t].x, k1 = kv[t+64].x, k2 = kv[t+128].x;
    float mx = fmaxf(fmaxf(k0, k1), k2);
    float mn = fminf(fminf(k0, k1), k2);
    #pragma unroll
    for (int off = 32; off; off >>= 1){
      mx = fmaxf(mx, __shfl_xor(mx, off));
      mn = fminf(mn, __shfl_xor(mn, off));
    }
    if (t == 0){ sred[3] = mx; sred[4] = mn; }
  }
  __syncthreads();
  if (t < 192){
    float hv_ = hq[t];
    float qi = __fmaf_rn(hv_, wq, bq);
    float mx = (qi >= 0.f) ? qi*sred[3] : qi*sred[4];
    float den = 0.f, num = 0.f;
    #pragma unroll 8
    for (int j = 0; j < 192; ++j){
      float2 K = kv[j];
      float e = __expf(__fmaf_rn(qi, K.x, -mx));
      den += e; num = __fmaf_rn(e, K.y, num);
    }
    h2s[t] = __fmaf_rn(num/den, wo, bo) + hv_;
  }
  __syncthreads();
  // ---- fl1: 192 -> 128, relu (2-way split over j) ----
  {
    const int n = t & 127;
    float acc = 0.f;
    const int i0 = h*96;
    #pragma unroll 8
    for (int k = 0; k < 96; ++k){
      int i = i0 + k;
      acc = __fmaf_rn(h2s[i], fl1_w[i*128 + n], acc);
    }
    red2[h][n].x = acc;
  }
  __syncthreads();
  if (t < 128) thr1[t] = reluf(red2[0][t].x + red2[1][t].x + fl1_b[t]);
  __syncthreads();
  // ---- fl2: 128 -> 32, tanh (4-way split) ----
  if (t < 128){
    const int n = t & 31, seg = t >> 5;
    float p = 0.f;
    #pragma unroll 8
    for (int k = 0; k < 32; ++k){
      int i = seg*32 + k;
      p = __fmaf_rn(thr1[i], fl2_w[i*32 + n], p);
    }
    eAs[t] = p;
  }
  __syncthreads();
  if (t < 32) hm[t] = tanh_fast(eAs[t] + eAs[t+32] + eAs[t+64] + eAs[t+96] + fl2_b[t]);
  __syncthreads();
  // ---- fl3: 32 -> 1, relu ----
  if (t < 64){
    float p = (t < 32) ? hm[t]*fl3_w[t] : 0.f;
    #pragma unroll
    for (int off = 32; off; off >>= 1) p += __shfl_xor(p, off);
    if (t == 0) out[b] = reluf(p + fl3_b[0]);
  }
}

extern "C" void kernel_launch(void* const* d_in, const int* in_sizes, int n_in,
                              void* d_out, int out_size, void* d_ws, size_t ws_size,
                              hipStream_t stream) {
  const int*   adj    = (const int*)  d_in[0];
  const float* feat   = (const float*)d_in[1];
  const float* timei  = (const float*)d_in[2];
  const float* ipop   = (const float*)d_in[3];
  const float* W1     = (const float*)d_in[4];
  const float* a1     = (const float*)d_in[5];
  const float* W2     = (const float*)d_in[6];
  const float* a2     = (const float*)d_in[7];
  const float* Weight = (const float*)d_in[8];
  const float* Wv     = (const float*)d_in[9];
  const float* wih0   = (const float*)d_in[10];
  const float* whh0   = (const float*)d_in[11];
  const float* bih0   = (const float*)d_in[12];
  const float* bhh0   = (const float*)d_in[13];
  const float* wih1   = (const float*)d_in[14];
  const float* whh1   = (const float*)d_in[15];
  const float* bih1   = (const float*)d_in[16];
  const float* bhh1   = (const float*)d_in[17];
  const float* mha_in_w  = (const float*)d_in[18];
  const float* mha_in_b  = (const float*)d_in[19];
  const float* mha_out_w = (const float*)d_in[20];
  const float* mha_out_b = (const float*)d_in[21];
  const float* fl1_w = (const float*)d_in[22];
  const float* fl1_b = (const float*)d_in[23];
  const float* fl2_w = (const float*)d_in[24];
  const float* fl2_b = (const float*)d_in[25];
  const float* fl3_w = (const float*)d_in[26];
  const float* fl3_b = (const float*)d_in[27];

  ull*   gpk    = (ull*)d_ws;                 // 512*256 ull = 1 MB
  ull*   gpkT   = gpk + 131072;               // 1 MB
  float* consts = (float*)(gpkT + 131072);    // 32 floats
  float* ip     = consts + 32;                // 512*64 floats

  pack_prep_kernel<<<521, 256, 0, stream>>>(adj, gpk, gpkT, W1, a1, W2, a2, consts,
                                            ipop, wih0, whh0, bih0, bhh0,
                                            wih1, whh1, bih1, bhh1, ip);
  gat_head_kernel<<<512, 256, 0, stream>>>(gpk, gpkT, feat, timei, Weight, Wv, consts, ip,
                                           mha_in_w, mha_in_b, mha_out_w, mha_out_b,
                                           fl1_w, fl1_b, fl2_w, fl2_b, fl3_w, fl3_b,
                                           (float*)d_out);
}

// Round 8
// 49.815 us; speedup vs baseline: 1.5134x; 1.2983x over previous
//
#include <hip/hip_runtime.h>
#include <math.h>

typedef unsigned int uint;
typedef unsigned long long ull;

#define L2E 1.44269504f

__device__ __forceinline__ float lrelu(float z){ return fmaxf(z, 0.5f*z); }
__device__ __forceinline__ float reluf(float z){ return fmaxf(z, 0.f); }
__device__ __forceinline__ float fexp(float z){ return __builtin_amdgcn_exp2f(z*L2E); }   // e^z, 2 inst
__device__ __forceinline__ float frcp(float z){ return __builtin_amdgcn_rcpf(z); }        // 1/z, 1 inst
__device__ __forceinline__ float tanh_n(float z){                                         // tanh, native
  return __fmaf_rn(2.f, __builtin_amdgcn_rcpf(1.f + __builtin_amdgcn_exp2f(-2.f*L2E*z)), -1.f);
}

// ================= K1: pack (0..511) + LSTM (512..519) + consts (520) =================
// gpk [b][i*2+h] (ull): bit k = adj[b][i][64h+k] > 0        (row-major)
// gpkT[b][j*2+h] (ull): bit k = adj[b][64h+k][j] > 0        (col-major)
// consts: [0]=c1 [1]=c2 [2..9]=P [10..17]=Q [18]=pA [19]=qA [20]=pB [21]=qB
__global__ __launch_bounds__(256) void pack_prep_kernel(
    const int* __restrict__ adj, ull* __restrict__ gpk, ull* __restrict__ gpkT,
    const float* __restrict__ W1, const float* __restrict__ a1,
    const float* __restrict__ W2, const float* __restrict__ a2,
    float* __restrict__ consts,
    const float* __restrict__ ipop,
    const float* __restrict__ wih0, const float* __restrict__ whh0,
    const float* __restrict__ bih0, const float* __restrict__ bhh0,
    const float* __restrict__ wih1, const float* __restrict__ whh1,
    const float* __restrict__ bih1, const float* __restrict__ bhh1,
    float* __restrict__ ip_out)
{
  const int bid = blockIdx.x, t = threadIdx.x;

  if (bid < 512){
    // ---- ballot pack: word W = w*64+ln lives in lane ln of wave w ----
    __shared__ ull rowW[256];
    const int w = t >> 6, ln = t & 63;
    const int* abase = adj + (((long)bid) << 14) + w*4096 + ln;
    ull myword = 0;
    #pragma unroll
    for (int blk = 0; blk < 8; ++blk){
      int v[8];
      #pragma unroll
      for (int q = 0; q < 8; ++q) v[q] = abase[(blk*8 + q)*64];   // coalesced, independent
      #pragma unroll
      for (int q = 0; q < 8; ++q){
        ull m = __ballot(v[q] > 0);
        const int it = blk*8 + q;
        myword = (ln == it) ? m : myword;     // cndmask: no exec-mask change
      }
    }
    rowW[t] = myword;
    gpk[bid*256 + t] = myword;
    __syncthreads();
    // ---- col words from LDS (all reads are wave-broadcast: free) ----
    const int j = t & 127, h2 = t >> 7;
    const int wsel = j >> 6, bsel = j & 63;
    ull outw = 0;
    #pragma unroll 8
    for (int k = 0; k < 64; ++k){
      outw |= ((rowW[(64*h2 + k)*2 + wsel] >> bsel) & 1ull) << k;
    }
    gpkT[bid*256 + j*2 + h2] = outw;
    return;
  }
  if (bid < 520){
    // ---- LSTM: 8 blocks x 64 threads = 512 sequences ----
    // log2e folded into gate weights: i,f,o scaled by -L2E; g by -2*L2E.
    // sigm(z) = rcp(1+exp2(z')), tanh(z) = 2*rcp(1+exp2(z''))-1 with pre-scaled inputs.
    if (t >= 64) return;
    const int b = (bid - 512)*64 + t;
    float wi0[4], wh0[4], bb0[4], wi1[4], wh1[4], bb1[4];
    #pragma unroll
    for (int k = 0; k < 4; ++k){
      const float s = (k == 2) ? -2.f*L2E : -L2E;
      wi0[k]=wih0[k]*s; wh0[k]=whh0[k]*s; bb0[k]=(bih0[k]+bhh0[k])*s;
      wi1[k]=wih1[k]*s; wh1[k]=whh1[k]*s; bb1[k]=(bih1[k]+bhh1[k])*s;
    }
    const float4* xsrc = (const float4*)(ipop + b*64);
    float4* hdst = (float4*)(ip_out + b*64);
    float4 xv = xsrc[0];
    float h1=0.f, c1v=0.f, h2=0.f, c2v=0.f;
    #pragma unroll
    for (int q = 0; q < 16; ++q){
      const float4 xc = xv;
      if (q < 15) xv = xsrc[q+1];            // prefetch next chunk under the chain
      float hout[4];
      #pragma unroll
      for (int s = 0; s < 4; ++s){
        const float x = (s==0) ? xc.x : (s==1) ? xc.y : (s==2) ? xc.z : xc.w;
        float gi = frcp(1.f + __builtin_amdgcn_exp2f(__fmaf_rn(x, wi0[0], __fmaf_rn(h1, wh0[0], bb0[0]))));
        float gf = frcp(1.f + __builtin_amdgcn_exp2f(__fmaf_rn(x, wi0[1], __fmaf_rn(h1, wh0[1], bb0[1]))));
        float gg = __fmaf_rn(2.f, frcp(1.f + __builtin_amdgcn_exp2f(__fmaf_rn(x, wi0[2], __fmaf_rn(h1, wh0[2], bb0[2])))), -1.f);
        float go = frcp(1.f + __builtin_amdgcn_exp2f(__fmaf_rn(x, wi0[3], __fmaf_rn(h1, wh0[3], bb0[3]))));
        c1v = gf*c1v + gi*gg;
        h1 = go*tanh_n(c1v);
        float hi2 = frcp(1.f + __builtin_amdgcn_exp2f(__fmaf_rn(h1, wi1[0], __fmaf_rn(h2, wh1[0], bb1[0]))));
        float hf2 = frcp(1.f + __builtin_amdgcn_exp2f(__fmaf_rn(h1, wi1[1], __fmaf_rn(h2, wh1[1], bb1[1]))));
        float hg2 = __fmaf_rn(2.f, frcp(1.f + __builtin_amdgcn_exp2f(__fmaf_rn(h1, wi1[2], __fmaf_rn(h2, wh1[2], bb1[2])))), -1.f);
        float ho2 = frcp(1.f + __builtin_amdgcn_exp2f(__fmaf_rn(h1, wi1[3], __fmaf_rn(h2, wh1[3], bb1[3]))));
        c2v = hf2*c2v + hi2*hg2;
        h2 = ho2*tanh_n(c2v);
        hout[s] = h2;
      }
      hdst[q] = make_float4(hout[0], hout[1], hout[2], hout[3]);
    }
    return;
  }
  // ---- consts block (cold path, plain math ok) ----
  {
    __shared__ float redA[256], redB[256];
    float s1 = 0.f, s2 = 0.f;
    for (int f = t; f < 512; f += 256){ float w = W1[f]; s1 += w*a1[f]; s2 += w*a1[512+f]; }
    redA[t] = s1; redB[t] = s2; __syncthreads();
    for (int st = 128; st > 0; st >>= 1){
      if (t < st){ redA[t] += redA[t+st]; redB[t] += redB[t+st]; }
      __syncthreads();
    }
    if (t == 0){ consts[0] = redA[0]; consts[1] = redB[0]; }
    __syncthreads();
    const int g = t >> 5, seg = t & 31;
    float accP = 0.f, accQ = 0.f;
    for (int k = 0; k < 16; ++k){
      int f = seg*16 + k;
      float w = W1[f];
      float v = w * W2[f*8 + g];
      if (w > 0.f) accP += v; else accQ += v;
    }
    redA[t] = accP; redB[t] = accQ; __syncthreads();
    for (int st = 16; st > 0; st >>= 1){
      if (seg < st){ redA[t] += redA[t+st]; redB[t] += redB[t+st]; }
      __syncthreads();
    }
    if (seg == 0){ consts[2+g] = redA[t]; consts[10+g] = redB[t]; }
    __syncthreads();
    if (t == 0){
      float pA=0.f,qA=0.f,pB=0.f,qB=0.f;
      for (int gg = 0; gg < 8; ++gg){
        pA += consts[2+gg]*a2[gg];   qA += consts[10+gg]*a2[gg];
        pB += consts[2+gg]*a2[8+gg]; qB += consts[10+gg]*a2[8+gg];
      }
      consts[18]=pA; consts[19]=qA; consts[20]=pB; consts[21]=qB;
    }
  }
}

// ================= K2: exp-factorized GAT1+GAT2 + pooling + MHA + MLP head =================
__global__ __launch_bounds__(256) void gat_head_kernel(
    const ull* __restrict__ gpk, const ull* __restrict__ gpkT,
    const float* __restrict__ feat, const float* __restrict__ timei,
    const float* __restrict__ Weight, const float* __restrict__ Wv,
    const float* __restrict__ consts, const float* __restrict__ ip,
    const float* __restrict__ mha_in_w, const float* __restrict__ mha_in_b,
    const float* __restrict__ mha_out_w, const float* __restrict__ mha_out_b,
    const float* __restrict__ fl1_w, const float* __restrict__ fl1_b,
    const float* __restrict__ fl2_w, const float* __restrict__ fl2_b,
    const float* __restrict__ fl3_w, const float* __restrict__ fl3_b,
    float* __restrict__ out)
{
  const int b = blockIdx.x, t = threadIdx.x;
  const int lane = t & 127, h = t >> 7;        // h in {0,1}: 64-chunk of the other axis

  __shared__ float  xs[128], tim[128], hm[128], eAs[128], thr1[128];
  __shared__ float2 f2a[128];                  // {E1_i, Eh_i}
  __shared__ float2 red2[2][128];              // pass partials / V-pair staging / fl1 partials
  __shared__ float4 q4[128];                   // {G1,G2,thr,-} then {Gp1,Gp2,Gn1,Gn2}
  __shared__ float4 pool4[2][128];             // row2 partials / pooling partials
  __shared__ float2 kv[192];
  __shared__ float  hq[192], h2s[192];
  __shared__ float  sred[8];

  const float c1 = consts[0], c2 = consts[1];
  const float pA = consts[18], qA = consts[19], pB = consts[20], qB = consts[21];

  // ---- phase 0: loads (masks into registers) ----
  float ipreg = 0.f;
  if (t < 128){ xs[t] = feat[b*128 + t]; tim[t] = timei[b*128 + t]; }
  if (t >= 192) ipreg = ip[b*64 + (t - 192)];
  const ull rowm = gpk [b*256 + lane*2 + h];   // bit k = adj[lane][64h+k]
  const ull colm = gpkT[b*256 + lane*2 + h];   // bit k = adj[64h+k][lane]
  __syncthreads();
  if (t < 64){
    float mx = fmaxf(xs[t], xs[t+64]);
    float mn = fminf(xs[t], xs[t+64]);
    #pragma unroll
    for (int off = 32; off; off >>= 1){
      mx = fmaxf(mx, __shfl_xor(mx, off));
      mn = fminf(mn, __shfl_xor(mn, off));
    }
    if (t == 0){ sred[0] = mx; sred[1] = mn; }
  }
  __syncthreads();

  // ---- phase 0b: per-node factors for GAT1 ----
  float myE1=0.f, myEh=0.f, myA=0.f, myB=0.f, mythr=0.f, myx=0.f;
  {
    const float rmax = (c1 >= 0.f) ? c1*sred[0] : c1*sred[1];
    if (t < 128){
      myx = xs[t];
      float r  = c1*myx;
      float cj = c2*myx;
      float cb = lrelu(rmax + cj);
      myE1  = fexp(r - rmax);
      myEh  = fexp(0.5f*(r - rmax));
      myA   = fexp(rmax + cj - cb);
      myB   = fexp(0.5f*(rmax + cj) - cb);
      mythr = fexp(-cj - rmax);
      f2a[t] = make_float2(myE1, myEh);
      thr1[t] = mythr;
    }
  }
  __syncthreads();

  // ---- GAT1 col pass: S1,S2 per column ----
  {
    const float thrj = thr1[lane];
    float s1 = 0.f, s2 = 0.f;
    #pragma unroll 8
    for (int k = 0; k < 64; ++k){
      float2 E = f2a[64*h + k];                // broadcast
      bool m = ((colm >> k) & 1ull);
      bool cond = (E.x >= thrj);
      s1 += (m &&  cond) ? E.x : 0.f;
      s2 += (m && !cond) ? E.y : 0.f;
    }
    red2[h][lane] = make_float2(s1, s2);
  }
  __syncthreads();
  // ---- combine: cr, per-column G table ----
  if (t < 128){
    float2 a = red2[0][t], bb = red2[1][t];
    float den = __fmaf_rn(myA, a.x + bb.x, myB*(a.y + bb.y));
    float cr = frcp(den);
    q4[t] = make_float4(myA*cr*myx, myB*cr*myx, mythr, 0.f);
  }
  __syncthreads();
  // ---- GAT1 row pass: u_i = E1_i*T1 + Eh_i*T2 ----
  {
    const float2 Eo = f2a[lane];
    float t1 = 0.f, t2 = 0.f;
    #pragma unroll 8
    for (int k = 0; k < 64; ++k){
      float4 G = q4[64*h + k];                 // broadcast
      bool m = ((rowm >> k) & 1ull);
      bool cond = (Eo.x >= G.z);
      t1 += (m &&  cond) ? G.x : 0.f;
      t2 += (m && !cond) ? G.y : 0.f;
    }
    red2[h][lane] = make_float2(t1, t2);
  }
  __syncthreads();
  // ---- u, eA, eB; eA max ----
  float u = 0.f, eBv = 0.f, eAv = 0.f;
  if (t < 128){
    float2 a = red2[0][t], bb = red2[1][t];
    u = __fmaf_rn(myE1, a.x + bb.x, myEh*(a.y + bb.y));
    eAv = (u >= 0.f ? pA : qA)*u;
    eBv = (u >= 0.f ? pB : qB)*u;
    eAs[t] = eAv;
  }
  __syncthreads();
  if (t < 64){
    float mx = fmaxf(eAs[t], eAs[t+64]);
    #pragma unroll
    for (int off = 32; off; off >>= 1) mx = fmaxf(mx, __shfl_xor(mx, off));
    if (t == 0) sred[2] = mx;
  }
  __syncthreads();
  // ---- per-node factors for GAT2 ----
  float myE1b=0.f, myEhb=0.f, myA2=0.f, myB2=0.f;
  {
    const float eAmax = sred[2];
    if (t < 128){
      float cb = lrelu(eAmax + eBv);
      myE1b = fexp(eAv - eAmax);
      myEhb = fexp(0.5f*(eAv - eAmax));
      myA2  = fexp(eAmax + eBv - cb);
      myB2  = fexp(0.5f*(eAmax + eBv) - cb);
      float th = fexp(-eBv - eAmax);
      f2a[t] = make_float2(myE1b, myEhb);
      thr1[t] = th;
    }
  }
  __syncthreads();
  // ---- GAT2 col pass ----
  {
    const float thrj = thr1[lane];
    float s1 = 0.f, s2 = 0.f;
    #pragma unroll 8
    for (int k = 0; k < 64; ++k){
      float2 E = f2a[64*h + k];
      bool m = ((colm >> k) & 1ull);
      bool cond = (E.x >= thrj);
      s1 += (m &&  cond) ? E.x : 0.f;
      s2 += (m && !cond) ? E.y : 0.f;
    }
    red2[h][lane] = make_float2(s1, s2);
  }
  __syncthreads();
  if (t < 128){
    float2 a = red2[0][t], bb = red2[1][t];
    float den = __fmaf_rn(myA2, a.x + bb.x, myB2*(a.y + bb.y));
    float cr = frcp(den);
    float up = fmaxf(u, 0.f), un = fminf(u, 0.f);
    q4[t] = make_float4(myA2*cr*up, myB2*cr*up, myA2*cr*un, myB2*cr*un);
  }
  __syncthreads();
  // ---- GAT2 row pass: sp/sn (4 accumulators) ----
  {
    const float2 Eo = f2a[lane];
    float sp1=0.f, sp2=0.f, sn1=0.f, sn2=0.f;
    #pragma unroll 8
    for (int k = 0; k < 64; ++k){
      int j = 64*h + k;
      float4 G = q4[j];
      float thj = thr1[j];
      bool m = ((rowm >> k) & 1ull);
      bool cond = (Eo.x >= thj);
      sp1 += (m &&  cond) ? G.x : 0.f;
      sp2 += (m && !cond) ? G.y : 0.f;
      sn1 += (m &&  cond) ? G.z : 0.f;
      sn2 += (m && !cond) ? G.w : 0.f;
    }
    pool4[h][lane] = make_float4(sp1, sp2, sn1, sn2);
  }
  __syncthreads();
  if (t < 128){
    float4 a = pool4[0][t], bb = pool4[1][t];
    float sp = __fmaf_rn(myE1b, a.x + bb.x, myEhb*(a.y + bb.y));
    float sn = __fmaf_rn(myE1b, a.z + bb.z, myEhb*(a.w + bb.w));
    float acc = 0.f;
    #pragma unroll
    for (int g = 0; g < 8; ++g) acc += reluf(__fmaf_rn(sp, consts[2+g], sn*consts[10+g]));
    hm[t] = 0.125f*acc;
  }
  __syncthreads();

  // ---- attention pooling over Weight/Wv (global, L2-resident) ----
  {
    const int n = lane;
    float a0=0.f, a1v=0.f, v0=0.f, v1=0.f;
    const int m0 = h*64;
    #pragma unroll 4
    for (int k = 0; k < 64; ++k){
      int m = m0 + k;
      float hmv = hm[m], tv = tim[m];
      float wg = Weight[(m<<7) + n], wvv = Wv[(m<<7) + n];
      a0 = __fmaf_rn(hmv, wg, a0); a1v = __fmaf_rn(tv, wg, a1v);
      v0 = __fmaf_rn(hmv, wvv, v0); v1 = __fmaf_rn(tv, wvv, v1);
    }
    pool4[h][n] = make_float4(a0, a1v, v0, v1);
  }
  __syncthreads();
  float att0 = 0.f, att1 = 0.f, rsv = 0.f;
  if (t < 128){
    float4 a = pool4[0][t], bb = pool4[1][t];
    float A0 = a.x + bb.x, A1 = a.y + bb.y;
    red2[0][t] = make_float2(a.z + bb.z, a.w + bb.w);   // {V0, V1}
    float mx = fmaxf(A0, A1);
    att0 = fexp(A0 - mx); att1 = fexp(A1 - mx);
    rsv = frcp(att0 + att1);
  }
  __syncthreads();
  if (t < 128){
    float r0, r1;
    if (t < 64){ r0 = red2[0][2*t].x;     r1 = red2[0][2*t+1].x; }
    else       { r0 = red2[0][2*t-128].y; r1 = red2[0][2*t-127].y; }
    hq[t] = (reluf(r0)*att0 + reluf(r1)*att1)*rsv;
  }
  if (t >= 192) hq[128 + (t - 192)] = ipreg;
  __syncthreads();

  // ---- MHA (dim-1) + residual ----
  const float wq = mha_in_w[0], wk = mha_in_w[1], wv = mha_in_w[2];
  const float bq = mha_in_b[0], bk = mha_in_b[1], bv = mha_in_b[2];
  const float wo = mha_out_w[0], bo = mha_out_b[0];
  if (t < 192){
    float hv_ = hq[t];
    kv[t] = make_float2(__fmaf_rn(hv_, wk, bk), __fmaf_rn(hv_, wv, bv));
  }
  __syncthreads();
  if (t < 64){
    float k0 = kv[t].x, k1 = kv[t+64].x, k2 = kv[t+128].x;
    float mx = fmaxf(fmaxf(k0, k1), k2);
    float mn = fminf(fminf(k0, k1), k2);
    #pragma unroll
    for (int off = 32; off; off >>= 1){
      mx = fmaxf(mx, __shfl_xor(mx, off));
      mn = fminf(mn, __shfl_xor(mn, off));
    }
    if (t == 0){ sred[3] = mx; sred[4] = mn; }
  }
  __syncthreads();
  if (t < 192){
    float hv_ = hq[t];
    float qi = __fmaf_rn(hv_, wq, bq);
    float mx = (qi >= 0.f) ? qi*sred[3] : qi*sred[4];
    const float qi2 = qi*L2E, mx2 = mx*L2E;      // pre-scaled for exp2
    float den = 0.f, num = 0.f;
    #pragma unroll 8
    for (int j = 0; j < 192; ++j){
      float2 K = kv[j];
      float e = __builtin_amdgcn_exp2f(__fmaf_rn(qi2, K.x, -mx2));
      den += e; num = __fmaf_rn(e, K.y, num);
    }
    h2s[t] = __fmaf_rn(num*frcp(den), wo, bo) + hv_;
  }
  __syncthreads();
  // ---- fl1: 192 -> 128, relu (2-way split over j) ----
  {
    const int n = t & 127;
    float acc = 0.f;
    const int i0 = h*96;
    #pragma unroll 8
    for (int k = 0; k < 96; ++k){
      int i = i0 + k;
      acc = __fmaf_rn(h2s[i], fl1_w[i*128 + n], acc);
    }
    red2[h][n].x = acc;
  }
  __syncthreads();
  if (t < 128) thr1[t] = reluf(red2[0][t].x + red2[1][t].x + fl1_b[t]);
  __syncthreads();
  // ---- fl2: 128 -> 32, tanh (4-way split) ----
  if (t < 128){
    const int n = t & 31, seg = t >> 5;
    float p = 0.f;
    #pragma unroll 8
    for (int k = 0; k < 32; ++k){
      int i = seg*32 + k;
      p = __fmaf_rn(thr1[i], fl2_w[i*32 + n], p);
    }
    eAs[t] = p;
  }
  __syncthreads();
  if (t < 32) hm[t] = tanh_n(eAs[t] + eAs[t+32] + eAs[t+64] + eAs[t+96] + fl2_b[t]);
  __syncthreads();
  // ---- fl3: 32 -> 1, relu ----
  if (t < 64){
    float p = (t < 32) ? hm[t]*fl3_w[t] : 0.f;
    #pragma unroll
    for (int off = 32; off; off >>= 1) p += __shfl_xor(p, off);
    if (t == 0) out[b] = reluf(p + fl3_b[0]);
  }
}

extern "C" void kernel_launch(void* const* d_in, const int* in_sizes, int n_in,
                              void* d_out, int out_size, void* d_ws, size_t ws_size,
                              hipStream_t stream) {
  const int*   adj    = (const int*)  d_in[0];
  const float* feat   = (const float*)d_in[1];
  const float* timei  = (const float*)d_in[2];
  const float* ipop   = (const float*)d_in[3];
  const float* W1     = (const float*)d_in[4];
  const float* a1     = (const float*)d_in[5];
  const float* W2     = (const float*)d_in[6];
  const float* a2     = (const float*)d_in[7];
  const float* Weight = (const float*)d_in[8];
  const float* Wv     = (const float*)d_in[9];
  const float* wih0   = (const float*)d_in[10];
  const float* whh0   = (const float*)d_in[11];
  const float* bih0   = (const float*)d_in[12];
  const float* bhh0   = (const float*)d_in[13];
  const float* wih1   = (const float*)d_in[14];
  const float* whh1   = (const float*)d_in[15];
  const float* bih1   = (const float*)d_in[16];
  const float* bhh1   = (const float*)d_in[17];
  const float* mha_in_w  = (const float*)d_in[18];
  const float* mha_in_b  = (const float*)d_in[19];
  const float* mha_out_w = (const float*)d_in[20];
  const float* mha_out_b = (const float*)d_in[21];
  const float* fl1_w = (const float*)d_in[22];
  const float* fl1_b = (const float*)d_in[23];
  const float* fl2_w = (const float*)d_in[24];
  const float* fl2_b = (const float*)d_in[25];
  const float* fl3_w = (const float*)d_in[26];
  const float* fl3_b = (const float*)d_in[27];

  ull*   gpk    = (ull*)d_ws;                 // 512*256 ull = 1 MB
  ull*   gpkT   = gpk + 131072;               // 1 MB
  float* consts = (float*)(gpkT + 131072);    // 32 floats
  float* ip     = consts + 32;                // 512*64 floats

  pack_prep_kernel<<<521, 256, 0, stream>>>(adj, gpk, gpkT, W1, a1, W2, a2, consts,
                                            ipop, wih0, whh0, bih0, bhh0,
                                            wih1, whh1, bih1, bhh1, ip);
  gat_head_kernel<<<512, 256, 0, stream>>>(gpk, gpkT, feat, timei, Weight, Wv, consts, ip,
                                           mha_in_w, mha_in_b, mha_out_w, mha_out_b,
                                           fl1_w, fl1_b, fl2_w, fl2_b, fl3_w, fl3_b,
                                           (float*)d_out);
}

// Round 9
// 49.362 us; speedup vs baseline: 1.5273x; 1.0092x over previous
//
#include <hip/hip_runtime.h>
#include <math.h>

typedef unsigned int uint;
typedef unsigned long long ull;

#define L2E 1.44269504f

__device__ __forceinline__ float lrelu(float z){ return fmaxf(z, 0.5f*z); }
__device__ __forceinline__ float reluf(float z){ return fmaxf(z, 0.f); }
__device__ __forceinline__ float fexp(float z){ return __builtin_amdgcn_exp2f(z*L2E); }
__device__ __forceinline__ float frcp(float z){ return __builtin_amdgcn_rcpf(z); }
__device__ __forceinline__ float tanh_n(float z){
  return __fmaf_rn(2.f, __builtin_amdgcn_rcpf(1.f + __builtin_amdgcn_exp2f(-2.f*L2E*z)), -1.f);
}

// ===== ONE kernel: pack + consts + LSTM (interleaved) + GAT1 + GAT2 + pooling + MHA + MLP =====
// 512 blocks x 256 threads, one batch per block.
__global__ __launch_bounds__(256) void fused_kernel(
    const int* __restrict__ adj, const float* __restrict__ feat,
    const float* __restrict__ timei,
    const float* __restrict__ Weight, const float* __restrict__ Wv,
    const float* __restrict__ W1, const float* __restrict__ a1,
    const float* __restrict__ W2, const float* __restrict__ a2,
    const float* __restrict__ ipop,
    const float* __restrict__ wih0, const float* __restrict__ whh0,
    const float* __restrict__ bih0, const float* __restrict__ bhh0,
    const float* __restrict__ wih1, const float* __restrict__ whh1,
    const float* __restrict__ bih1, const float* __restrict__ bhh1,
    const float* __restrict__ mha_in_w, const float* __restrict__ mha_in_b,
    const float* __restrict__ mha_out_w, const float* __restrict__ mha_out_b,
    const float* __restrict__ fl1_w, const float* __restrict__ fl1_b,
    const float* __restrict__ fl2_w, const float* __restrict__ fl2_b,
    const float* __restrict__ fl3_w, const float* __restrict__ fl3_b,
    float* __restrict__ out)
{
  const int b = blockIdx.x, t = threadIdx.x;
  const int lane = t & 127, h = t >> 7;        // h in {0,1}
  const int wv = t >> 6, ln = t & 63;

  __shared__ ull   rowW[256];                  // rowW[i*2+ch] bit k = adj[i][64ch+k]
  __shared__ float xs[128], tim[128], hm[128], eAs[128], thr1[128];
  __shared__ float2 f2a[128];
  __shared__ float2 red2[2][128];
  __shared__ float4 q4[128];
  __shared__ float4 pool4[2][128];
  __shared__ float2 kv[192];
  __shared__ float  hq[192], h2s[192];
  __shared__ float  sred[8];
  __shared__ float  cpart[4][2];               // per-wave c1,c2 partials
  __shared__ float  pqpart[4][16];             // per-wave P/Q partials
  __shared__ float  cons[24];                  // 0,1=c1,c2; 2..9=P; 10..17=Q; 18..21=pA,qA,pB,qB
  __shared__ float  ips[64];                   // LSTM output for this batch

  // ================= region A (pre-B1) =================
  if (t < 128){ xs[t] = feat[b*128 + t]; tim[t] = timei[b*128 + t]; }

  // a2 prefetch for the consts finalizer
  float a2reg[16];
  if (t == 0){
    #pragma unroll
    for (int g = 0; g < 16; ++g) a2reg[g] = a2[g];
  }

  // LSTM prologue (thread 255 only): scaled weights + first x pair
  float h1v=0.f, c1s=0.f, h2v=0.f, c2s=0.f;
  float wi0s[4], wh0s[4], bb0s[4], wi1s[4], wh1s[4], bb1s[4];
  const float4* xsrc4 = (const float4*)(ipop + b*64);
  float4 xcur0, xcur1;
  if (t == 255){
    #pragma unroll
    for (int k = 0; k < 4; ++k){
      const float s = (k == 2) ? -2.f*L2E : -L2E;
      wi0s[k]=wih0[k]*s; wh0s[k]=whh0[k]*s; bb0s[k]=(bih0[k]+bhh0[k])*s;
      wi1s[k]=wih1[k]*s; wh1s[k]=whh1[k]*s; bb1s[k]=(bih1[k]+bhh1[k])*s;
    }
    xcur0 = xsrc4[0]; xcur1 = xsrc4[1];
  }
  auto lstm8 = [&](int c){
    if (t != 255) return;
    const float4 xa = xcur0, xb = xcur1;
    if (c < 7){ xcur0 = xsrc4[2*c+2]; xcur1 = xsrc4[2*c+3]; }
    float o[8];
    #pragma unroll
    for (int si = 0; si < 8; ++si){
      const float x = (si==0)?xa.x:(si==1)?xa.y:(si==2)?xa.z:(si==3)?xa.w:
                      (si==4)?xb.x:(si==5)?xb.y:(si==6)?xb.z:xb.w;
      float gi = frcp(1.f + __builtin_amdgcn_exp2f(__fmaf_rn(x, wi0s[0], __fmaf_rn(h1v, wh0s[0], bb0s[0]))));
      float gf = frcp(1.f + __builtin_amdgcn_exp2f(__fmaf_rn(x, wi0s[1], __fmaf_rn(h1v, wh0s[1], bb0s[1]))));
      float gg = __fmaf_rn(2.f, frcp(1.f + __builtin_amdgcn_exp2f(__fmaf_rn(x, wi0s[2], __fmaf_rn(h1v, wh0s[2], bb0s[2])))), -1.f);
      float go = frcp(1.f + __builtin_amdgcn_exp2f(__fmaf_rn(x, wi0s[3], __fmaf_rn(h1v, wh0s[3], bb0s[3]))));
      c1s = gf*c1s + gi*gg;  h1v = go*tanh_n(c1s);
      float hi = frcp(1.f + __builtin_amdgcn_exp2f(__fmaf_rn(h1v, wi1s[0], __fmaf_rn(h2v, wh1s[0], bb1s[0]))));
      float hf = frcp(1.f + __builtin_amdgcn_exp2f(__fmaf_rn(h1v, wi1s[1], __fmaf_rn(h2v, wh1s[1], bb1s[1]))));
      float hg = __fmaf_rn(2.f, frcp(1.f + __builtin_amdgcn_exp2f(__fmaf_rn(h1v, wi1s[2], __fmaf_rn(h2v, wh1s[2], bb1s[2])))), -1.f);
      float ho = frcp(1.f + __builtin_amdgcn_exp2f(__fmaf_rn(h1v, wi1s[3], __fmaf_rn(h2v, wh1s[3], bb1s[3]))));
      c2s = hf*c2s + hi*hg;  h2v = ho*tanh_n(c2s);
      o[si] = h2v;
    }
    #pragma unroll
    for (int si = 0; si < 8; ++si) ips[8*c + si] = o[si];
  };

  // ballot pack (all 256 threads; round-6 proven pattern)
  {
    const int* abase = adj + (((long)b) << 14) + wv*4096 + ln;
    ull myword = 0;
    #pragma unroll
    for (int blk = 0; blk < 8; ++blk){
      int v[8];
      #pragma unroll
      for (int q = 0; q < 8; ++q) v[q] = abase[(blk*8 + q)*64];
      #pragma unroll
      for (int q = 0; q < 8; ++q){
        ull m = __ballot(v[q] > 0);
        myword = (ln == blk*8 + q) ? m : myword;
      }
    }
    rowW[t] = myword;
  }

  // consts partials: c1,c2
  {
    float w0 = W1[t], w1 = W1[t+256];
    float s1 = __fmaf_rn(w0, a1[t],     w1*a1[t+256]);
    float s2 = __fmaf_rn(w0, a1[512+t], w1*a1[768+t]);
    #pragma unroll
    for (int off = 32; off; off >>= 1){ s1 += __shfl_xor(s1, off); s2 += __shfl_xor(s2, off); }
    if (ln == 0){ cpart[wv][0] = s1; cpart[wv][1] = s2; }
  }
  // consts partials: P,Q
  {
    float accP[8], accQ[8];
    #pragma unroll
    for (int g = 0; g < 8; ++g){ accP[g] = 0.f; accQ[g] = 0.f; }
    #pragma unroll
    for (int e = 0; e < 2; ++e){
      const int f = 2*t + e;
      const float w = W1[f];
      const float wp = fmaxf(w, 0.f), wn = fminf(w, 0.f);
      const float4 A = *(const float4*)(W2 + f*8);
      const float4 Bv = *(const float4*)(W2 + f*8 + 4);
      accP[0]=__fmaf_rn(wp,A.x,accP[0]);  accQ[0]=__fmaf_rn(wn,A.x,accQ[0]);
      accP[1]=__fmaf_rn(wp,A.y,accP[1]);  accQ[1]=__fmaf_rn(wn,A.y,accQ[1]);
      accP[2]=__fmaf_rn(wp,A.z,accP[2]);  accQ[2]=__fmaf_rn(wn,A.z,accQ[2]);
      accP[3]=__fmaf_rn(wp,A.w,accP[3]);  accQ[3]=__fmaf_rn(wn,A.w,accQ[3]);
      accP[4]=__fmaf_rn(wp,Bv.x,accP[4]); accQ[4]=__fmaf_rn(wn,Bv.x,accQ[4]);
      accP[5]=__fmaf_rn(wp,Bv.y,accP[5]); accQ[5]=__fmaf_rn(wn,Bv.y,accQ[5]);
      accP[6]=__fmaf_rn(wp,Bv.z,accP[6]); accQ[6]=__fmaf_rn(wn,Bv.z,accQ[6]);
      accP[7]=__fmaf_rn(wp,Bv.w,accP[7]); accQ[7]=__fmaf_rn(wn,Bv.w,accQ[7]);
    }
    #pragma unroll
    for (int g = 0; g < 8; ++g){
      float p = accP[g], q = accQ[g];
      #pragma unroll
      for (int off = 32; off; off >>= 1){ p += __shfl_xor(p, off); q += __shfl_xor(q, off); }
      if (ln == 0){ pqpart[wv][g] = p; pqpart[wv][8+g] = q; }
    }
  }
  __syncthreads();   // B1

  // ================= region B =================
  const ull rowm = rowW[lane*2 + h];           // bit k = adj[lane][64h+k]
  ull colm = 0;                                // bit k = adj[64h+k][lane]
  {
    const int wsel = lane >> 6, bsel = lane & 63;
    #pragma unroll 8
    for (int k = 0; k < 64; ++k)
      colm |= ((rowW[(64*h + k)*2 + wsel] >> bsel) & 1ull) << k;
  }
  if (t < 64){
    float mx = fmaxf(xs[t], xs[t+64]);
    float mn = fminf(xs[t], xs[t+64]);
    #pragma unroll
    for (int off = 32; off; off >>= 1){
      mx = fmaxf(mx, __shfl_xor(mx, off));
      mn = fminf(mn, __shfl_xor(mn, off));
    }
    if (t == 0){ sred[0] = mx; sred[1] = mn; }
  }
  if (t == 0){
    float c1v = cpart[0][0]+cpart[1][0]+cpart[2][0]+cpart[3][0];
    float c2v = cpart[0][1]+cpart[1][1]+cpart[2][1]+cpart[3][1];
    cons[0] = c1v; cons[1] = c2v;
    float pAx=0.f, qAx=0.f, pBx=0.f, qBx=0.f;
    #pragma unroll
    for (int g = 0; g < 8; ++g){
      float P = pqpart[0][g]+pqpart[1][g]+pqpart[2][g]+pqpart[3][g];
      float Q = pqpart[0][8+g]+pqpart[1][8+g]+pqpart[2][8+g]+pqpart[3][8+g];
      cons[2+g] = P; cons[10+g] = Q;
      pAx = __fmaf_rn(P, a2reg[g],   pAx);  qAx = __fmaf_rn(Q, a2reg[g],   qAx);
      pBx = __fmaf_rn(P, a2reg[8+g], pBx);  qBx = __fmaf_rn(Q, a2reg[8+g], qBx);
    }
    cons[18]=pAx; cons[19]=qAx; cons[20]=pBx; cons[21]=qBx;
  }
  lstm8(0);
  __syncthreads();   // B2

  // ================= GAT1 factors =================
  float myE1=0.f, myEh=0.f, myA=0.f, myB=0.f, mythr=0.f, myx=0.f;
  {
    const float c1 = cons[0], c2 = cons[1];
    const float rmax = (c1 >= 0.f) ? c1*sred[0] : c1*sred[1];
    if (t < 128){
      myx = xs[t];
      float r  = c1*myx;
      float cj = c2*myx;
      float cb = lrelu(rmax + cj);
      myE1  = fexp(r - rmax);
      myEh  = fexp(0.5f*(r - rmax));
      myA   = fexp(rmax + cj - cb);
      myB   = fexp(0.5f*(rmax + cj) - cb);
      mythr = fexp(-cj - rmax);
      f2a[t] = make_float2(myE1, myEh);
      thr1[t] = mythr;
    }
  }
  lstm8(1);
  __syncthreads();   // B3

  // ---- GAT1 col pass ----
  {
    const float thrj = thr1[lane];
    float s1 = 0.f, s2 = 0.f;
    #pragma unroll 8
    for (int k = 0; k < 64; ++k){
      float2 E = f2a[64*h + k];
      bool m = ((colm >> k) & 1ull);
      bool cond = (E.x >= thrj);
      s1 += (m &&  cond) ? E.x : 0.f;
      s2 += (m && !cond) ? E.y : 0.f;
    }
    red2[h][lane] = make_float2(s1, s2);
  }
  lstm8(2);
  __syncthreads();   // B4

  if (t < 128){
    float2 a = red2[0][t], bb = red2[1][t];
    float den = __fmaf_rn(myA, a.x + bb.x, myB*(a.y + bb.y));
    float cr = frcp(den);
    q4[t] = make_float4(myA*cr*myx, myB*cr*myx, mythr, 0.f);
  }
  lstm8(3);
  __syncthreads();   // B5

  // ---- GAT1 row pass ----
  {
    const float2 Eo = f2a[lane];
    float t1 = 0.f, t2 = 0.f;
    #pragma unroll 8
    for (int k = 0; k < 64; ++k){
      float4 G = q4[64*h + k];
      bool m = ((rowm >> k) & 1ull);
      bool cond = (Eo.x >= G.z);
      t1 += (m &&  cond) ? G.x : 0.f;
      t2 += (m && !cond) ? G.y : 0.f;
    }
    red2[h][lane] = make_float2(t1, t2);
  }
  lstm8(4);
  __syncthreads();   // B6

  float u = 0.f, eBv = 0.f, eAv = 0.f;
  if (t < 128){
    float2 a = red2[0][t], bb = red2[1][t];
    u = __fmaf_rn(myE1, a.x + bb.x, myEh*(a.y + bb.y));
    eAv = (u >= 0.f ? cons[18] : cons[19])*u;
    eBv = (u >= 0.f ? cons[20] : cons[21])*u;
    eAs[t] = eAv;
  }
  lstm8(5);
  __syncthreads();   // B7

  if (t < 64){
    float mx = fmaxf(eAs[t], eAs[t+64]);
    #pragma unroll
    for (int off = 32; off; off >>= 1) mx = fmaxf(mx, __shfl_xor(mx, off));
    if (t == 0) sred[2] = mx;
  }
  lstm8(6);
  __syncthreads();   // B8

  // ================= GAT2 factors =================
  float myE1b=0.f, myEhb=0.f, myA2=0.f, myB2=0.f;
  {
    const float eAmax = sred[2];
    if (t < 128){
      float cb = lrelu(eAmax + eBv);
      myE1b = fexp(eAv - eAmax);
      myEhb = fexp(0.5f*(eAv - eAmax));
      myA2  = fexp(eAmax + eBv - cb);
      myB2  = fexp(0.5f*(eAmax + eBv) - cb);
      float th = fexp(-eBv - eAmax);
      f2a[t] = make_float2(myE1b, myEhb);
      thr1[t] = th;
    }
  }
  lstm8(7);          // LSTM complete: ips[0..63] written
  __syncthreads();   // B9

  // ---- GAT2 col pass ----
  {
    const float thrj = thr1[lane];
    float s1 = 0.f, s2 = 0.f;
    #pragma unroll 8
    for (int k = 0; k < 64; ++k){
      float2 E = f2a[64*h + k];
      bool m = ((colm >> k) & 1ull);
      bool cond = (E.x >= thrj);
      s1 += (m &&  cond) ? E.x : 0.f;
      s2 += (m && !cond) ? E.y : 0.f;
    }
    red2[h][lane] = make_float2(s1, s2);
  }
  __syncthreads();   // B10

  if (t < 128){
    float2 a = red2[0][t], bb = red2[1][t];
    float den = __fmaf_rn(myA2, a.x + bb.x, myB2*(a.y + bb.y));
    float cr = frcp(den);
    float up = fmaxf(u, 0.f), un = fminf(u, 0.f);
    q4[t] = make_float4(myA2*cr*up, myB2*cr*up, myA2*cr*un, myB2*cr*un);
  }
  __syncthreads();   // B11

  // ---- GAT2 row pass ----
  {
    const float2 Eo = f2a[lane];
    float sp1=0.f, sp2=0.f, sn1=0.f, sn2=0.f;
    #pragma unroll 8
    for (int k = 0; k < 64; ++k){
      int j = 64*h + k;
      float4 G = q4[j];
      float thj = thr1[j];
      bool m = ((rowm >> k) & 1ull);
      bool cond = (Eo.x >= thj);
      sp1 += (m &&  cond) ? G.x : 0.f;
      sp2 += (m && !cond) ? G.y : 0.f;
      sn1 += (m &&  cond) ? G.z : 0.f;
      sn2 += (m && !cond) ? G.w : 0.f;
    }
    pool4[h][lane] = make_float4(sp1, sp2, sn1, sn2);
  }
  __syncthreads();   // B12

  if (t < 128){
    float4 a = pool4[0][t], bb = pool4[1][t];
    float sp = __fmaf_rn(myE1b, a.x + bb.x, myEhb*(a.y + bb.y));
    float sn = __fmaf_rn(myE1b, a.z + bb.z, myEhb*(a.w + bb.w));
    float acc = 0.f;
    #pragma unroll
    for (int g = 0; g < 8; ++g) acc += reluf(__fmaf_rn(sp, cons[2+g], sn*cons[10+g]));
    hm[t] = 0.125f*acc;
  }
  __syncthreads();   // B13

  // ---- attention pooling ----
  {
    const int n = lane;
    float a0=0.f, a1v=0.f, v0=0.f, v1=0.f;
    const int m0 = h*64;
    #pragma unroll 4
    for (int k = 0; k < 64; ++k){
      int m = m0 + k;
      float hmv = hm[m], tv = tim[m];
      float wg = Weight[(m<<7) + n], wvv = Wv[(m<<7) + n];
      a0 = __fmaf_rn(hmv, wg, a0); a1v = __fmaf_rn(tv, wg, a1v);
      v0 = __fmaf_rn(hmv, wvv, v0); v1 = __fmaf_rn(tv, wvv, v1);
    }
    pool4[h][n] = make_float4(a0, a1v, v0, v1);
  }
  __syncthreads();   // B14

  float att0 = 0.f, att1 = 0.f, rsv = 0.f;
  if (t < 128){
    float4 a = pool4[0][t], bb = pool4[1][t];
    float A0 = a.x + bb.x, A1 = a.y + bb.y;
    red2[0][t] = make_float2(a.z + bb.z, a.w + bb.w);
    float mx = fmaxf(A0, A1);
    att0 = fexp(A0 - mx); att1 = fexp(A1 - mx);
    rsv = frcp(att0 + att1);
  }
  __syncthreads();   // B15

  if (t < 128){
    float r0, r1;
    if (t < 64){ r0 = red2[0][2*t].x;     r1 = red2[0][2*t+1].x; }
    else       { r0 = red2[0][2*t-128].y; r1 = red2[0][2*t-127].y; }
    hq[t] = (reluf(r0)*att0 + reluf(r1)*att1)*rsv;
  }
  if (t >= 192) hq[128 + (t - 192)] = ips[t - 192];
  __syncthreads();   // B16

  // ---- MHA ----
  const float wq = mha_in_w[0], wk = mha_in_w[1], wvv_ = mha_in_w[2];
  const float bq = mha_in_b[0], bk = mha_in_b[1], bv = mha_in_b[2];
  const float wo = mha_out_w[0], bo = mha_out_b[0];
  if (t < 192){
    float hv_ = hq[t];
    kv[t] = make_float2(__fmaf_rn(hv_, wk, bk), __fmaf_rn(hv_, wvv_, bv));
  }
  __syncthreads();   // B17

  if (t < 64){
    float k0 = kv[t].x, k1 = kv[t+64].x, k2 = kv[t+128].x;
    float mx = fmaxf(fmaxf(k0, k1), k2);
    float mn = fminf(fminf(k0, k1), k2);
    #pragma unroll
    for (int off = 32; off; off >>= 1){
      mx = fmaxf(mx, __shfl_xor(mx, off));
      mn = fminf(mn, __shfl_xor(mn, off));
    }
    if (t == 0){ sred[3] = mx; sred[4] = mn; }
  }
  __syncthreads();   // B18

  if (t < 192){
    float hv_ = hq[t];
    float qi = __fmaf_rn(hv_, wq, bq);
    float mx = (qi >= 0.f) ? qi*sred[3] : qi*sred[4];
    const float qi2 = qi*L2E, mx2 = mx*L2E;
    float den = 0.f, num = 0.f;
    #pragma unroll 8
    for (int j = 0; j < 192; ++j){
      float2 K = kv[j];
      float e = __builtin_amdgcn_exp2f(__fmaf_rn(qi2, K.x, -mx2));
      den += e; num = __fmaf_rn(e, K.y, num);
    }
    h2s[t] = __fmaf_rn(num*frcp(den), wo, bo) + hv_;
  }
  __syncthreads();   // B19

  // ---- fl1: 192->128 (2-way split) ----
  {
    const int n = t & 127;
    float acc = 0.f;
    const int i0 = h*96;
    #pragma unroll 8
    for (int k = 0; k < 96; ++k){
      int i = i0 + k;
      acc = __fmaf_rn(h2s[i], fl1_w[i*128 + n], acc);
    }
    red2[h][n].x = acc;
  }
  __syncthreads();   // B20

  if (t < 128) thr1[t] = reluf(red2[0][t].x + red2[1][t].x + fl1_b[t]);
  __syncthreads();   // B21

  // ---- fl2: 128->32 (4-way split) ----
  if (t < 128){
    const int n = t & 31, seg = t >> 5;
    float p = 0.f;
    #pragma unroll 8
    for (int k = 0; k < 32; ++k){
      int i = seg*32 + k;
      p = __fmaf_rn(thr1[i], fl2_w[i*32 + n], p);
    }
    eAs[t] = p;
  }
  __syncthreads();   // B22

  if (t < 32) hm[t] = tanh_n(eAs[t] + eAs[t+32] + eAs[t+64] + eAs[t+96] + fl2_b[t]);
  __syncthreads();   // B23

  // ---- fl3: 32->1 ----
  if (t < 64){
    float p = (t < 32) ? hm[t]*fl3_w[t] : 0.f;
    #pragma unroll
    for (int off = 32; off; off >>= 1) p += __shfl_xor(p, off);
    if (t == 0) out[b] = reluf(p + fl3_b[0]);
  }
}

extern "C" void kernel_launch(void* const* d_in, const int* in_sizes, int n_in,
                              void* d_out, int out_size, void* d_ws, size_t ws_size,
                              hipStream_t stream) {
  const int*   adj    = (const int*)  d_in[0];
  const float* feat   = (const float*)d_in[1];
  const float* timei  = (const float*)d_in[2];
  const float* ipop   = (const float*)d_in[3];
  const float* W1     = (const float*)d_in[4];
  const float* a1     = (const float*)d_in[5];
  const float* W2     = (const float*)d_in[6];
  const float* a2     = (const float*)d_in[7];
  const float* Weight = (const float*)d_in[8];
  const float* Wv     = (const float*)d_in[9];
  const float* wih0   = (const float*)d_in[10];
  const float* whh0   = (const float*)d_in[11];
  const float* bih0   = (const float*)d_in[12];
  const float* bhh0   = (const float*)d_in[13];
  const float* wih1   = (const float*)d_in[14];
  const float* whh1   = (const float*)d_in[15];
  const float* bih1   = (const float*)d_in[16];
  const float* bhh1   = (const float*)d_in[17];
  const float* mha_in_w  = (const float*)d_in[18];
  const float* mha_in_b  = (const float*)d_in[19];
  const float* mha_out_w = (const float*)d_in[20];
  const float* mha_out_b = (const float*)d_in[21];
  const float* fl1_w = (const float*)d_in[22];
  const float* fl1_b = (const float*)d_in[23];
  const float* fl2_w = (const float*)d_in[24];
  const float* fl2_b = (const float*)d_in[25];
  const float* fl3_w = (const float*)d_in[26];
  const float* fl3_b = (const float*)d_in[27];

  fused_kernel<<<512, 256, 0, stream>>>(adj, feat, timei, Weight, Wv,
                                        W1, a1, W2, a2, ipop,
                                        wih0, whh0, bih0, bhh0,
                                        wih1, whh1, bih1, bhh1,
                                        mha_in_w, mha_in_b, mha_out_w, mha_out_b,
                                        fl1_w, fl1_b, fl2_w, fl2_b, fl3_w, fl3_b,
                                        (float*)d_out);
}

// Round 10
// 43.900 us; speedup vs baseline: 1.7174x; 1.1244x over previous
//
#include <hip/hip_runtime.h>
#include <math.h>

typedef unsigned int uint;
typedef unsigned long long ull;

#define L2E 1.44269504f

__device__ __forceinline__ float lrelu(float z){ return fmaxf(z, 0.5f*z); }
__device__ __forceinline__ float reluf(float z){ return fmaxf(z, 0.f); }
__device__ __forceinline__ float fexp(float z){ return __builtin_amdgcn_exp2f(z*L2E); }
__device__ __forceinline__ float frcp(float z){ return __builtin_amdgcn_rcpf(z); }
__device__ __forceinline__ float tanh_n(float z){
  return __fmaf_rn(2.f, __builtin_amdgcn_rcpf(1.f + __builtin_amdgcn_exp2f(-2.f*L2E*z)), -1.f);
}

// ===== ONE kernel, 512 blocks x 512 threads: pack + consts + LSTM + GAT1 + GAT2 + pool + MHA + MLP =====
__global__ __launch_bounds__(512) void fused_kernel(
    const int* __restrict__ adj, const float* __restrict__ feat,
    const float* __restrict__ timei,
    const float* __restrict__ Weight, const float* __restrict__ Wv,
    const float* __restrict__ W1, const float* __restrict__ a1,
    const float* __restrict__ W2, const float* __restrict__ a2,
    const float* __restrict__ ipop,
    const float* __restrict__ wih0, const float* __restrict__ whh0,
    const float* __restrict__ bih0, const float* __restrict__ bhh0,
    const float* __restrict__ wih1, const float* __restrict__ whh1,
    const float* __restrict__ bih1, const float* __restrict__ bhh1,
    const float* __restrict__ mha_in_w, const float* __restrict__ mha_in_b,
    const float* __restrict__ mha_out_w, const float* __restrict__ mha_out_b,
    const float* __restrict__ fl1_w, const float* __restrict__ fl1_b,
    const float* __restrict__ fl2_w, const float* __restrict__ fl2_b,
    const float* __restrict__ fl3_w, const float* __restrict__ fl3_b,
    float* __restrict__ out)
{
  const int b = blockIdx.x, t = threadIdx.x;
  const int lane = t & 127, h = t >> 7;        // h in {0,1,2,3}: 32-chunk of the other axis
  const int wv = t >> 6, ln = t & 63;          // wave id / lane id

  __shared__ ull   rowW[256];                  // rowW[i*2+ch] bit k = adj[i][64ch+k]
  __shared__ float xs[128], tim[128], hm[128], eAs[128], thr1[128];
  __shared__ float2 f2a[128];
  __shared__ float2 red4[4][128];
  __shared__ float4 q4[128];
  __shared__ float4 pool4[4][128];
  __shared__ float2 kv[192];
  __shared__ float  hq[192], h2s[192];
  __shared__ float  pden[2][192], pnum[2][192];
  __shared__ float  sred[8];
  __shared__ float  cpart[8][2];
  __shared__ float  pqpart[8][16];
  __shared__ float  cons[24];                  // 0,1=c1,c2; 2..9=P; 10..17=Q; 18..21=pA,qA,pB,qB
  __shared__ float  ips[64];                   // LSTM output

  // ================= region A (pre-B1) =================
  if (t < 128){ xs[t] = feat[b*128 + t]; tim[t] = timei[b*128 + t]; }

  float a2reg[16];
  if (t == 0){
    #pragma unroll
    for (int g = 0; g < 16; ++g) a2reg[g] = a2[g];
  }

  // LSTM prologue (thread 511 only)
  float h1v=0.f, c1s=0.f, h2v=0.f, c2s=0.f;
  float wi0s[4], wh0s[4], bb0s[4], wi1s[4], wh1s[4], bb1s[4];
  const float4* xsrc4 = (const float4*)(ipop + b*64);
  float4 xcur0, xcur1;
  if (t == 511){
    #pragma unroll
    for (int k = 0; k < 4; ++k){
      const float s = (k == 2) ? -2.f*L2E : -L2E;
      wi0s[k]=wih0[k]*s; wh0s[k]=whh0[k]*s; bb0s[k]=(bih0[k]+bhh0[k])*s;
      wi1s[k]=wih1[k]*s; wh1s[k]=whh1[k]*s; bb1s[k]=(bih1[k]+bhh1[k])*s;
    }
    xcur0 = xsrc4[0]; xcur1 = xsrc4[1];
  }
  auto lstm8 = [&](int c){
    if (t != 511) return;
    const float4 xa = xcur0, xb = xcur1;
    if (c < 7){ xcur0 = xsrc4[2*c+2]; xcur1 = xsrc4[2*c+3]; }
    float o[8];
    #pragma unroll
    for (int si = 0; si < 8; ++si){
      const float x = (si==0)?xa.x:(si==1)?xa.y:(si==2)?xa.z:(si==3)?xa.w:
                      (si==4)?xb.x:(si==5)?xb.y:(si==6)?xb.z:xb.w;
      float gi = frcp(1.f + __builtin_amdgcn_exp2f(__fmaf_rn(x, wi0s[0], __fmaf_rn(h1v, wh0s[0], bb0s[0]))));
      float gf = frcp(1.f + __builtin_amdgcn_exp2f(__fmaf_rn(x, wi0s[1], __fmaf_rn(h1v, wh0s[1], bb0s[1]))));
      float gg = __fmaf_rn(2.f, frcp(1.f + __builtin_amdgcn_exp2f(__fmaf_rn(x, wi0s[2], __fmaf_rn(h1v, wh0s[2], bb0s[2])))), -1.f);
      float go = frcp(1.f + __builtin_amdgcn_exp2f(__fmaf_rn(x, wi0s[3], __fmaf_rn(h1v, wh0s[3], bb0s[3]))));
      c1s = gf*c1s + gi*gg;  h1v = go*tanh_n(c1s);
      float hi = frcp(1.f + __builtin_amdgcn_exp2f(__fmaf_rn(h1v, wi1s[0], __fmaf_rn(h2v, wh1s[0], bb1s[0]))));
      float hf = frcp(1.f + __builtin_amdgcn_exp2f(__fmaf_rn(h1v, wi1s[1], __fmaf_rn(h2v, wh1s[1], bb1s[1]))));
      float hg = __fmaf_rn(2.f, frcp(1.f + __builtin_amdgcn_exp2f(__fmaf_rn(h1v, wi1s[2], __fmaf_rn(h2v, wh1s[2], bb1s[2])))), -1.f);
      float ho = frcp(1.f + __builtin_amdgcn_exp2f(__fmaf_rn(h1v, wi1s[3], __fmaf_rn(h2v, wh1s[3], bb1s[3])))) ;
      c2s = hf*c2s + hi*hg;  h2v = ho*tanh_n(c2s);
      o[si] = h2v;
    }
    #pragma unroll
    for (int si = 0; si < 8; ++si) ips[8*c + si] = o[si];
  };

  // ballot pack: wave wv packs words [wv*32, wv*32+32); 32 coalesced loads/thread
  {
    const int* abase = adj + (((long)b) << 14) + wv*2048 + ln;
    ull myword = 0;
    #pragma unroll
    for (int blk = 0; blk < 4; ++blk){
      int v[8];
      #pragma unroll
      for (int q = 0; q < 8; ++q) v[q] = abase[(blk*8 + q)*64];
      #pragma unroll
      for (int q = 0; q < 8; ++q){
        ull m = __ballot(v[q] > 0);
        myword = (ln == blk*8 + q) ? m : myword;
      }
    }
    if (ln < 32) rowW[wv*32 + ln] = myword;
  }

  // consts partials: c1,c2 (one element per thread)
  {
    float w0 = W1[t];
    float s1 = w0*a1[t];
    float s2 = w0*a1[512+t];
    #pragma unroll
    for (int off = 32; off; off >>= 1){ s1 += __shfl_xor(s1, off); s2 += __shfl_xor(s2, off); }
    if (ln == 0){ cpart[wv][0] = s1; cpart[wv][1] = s2; }
  }
  // consts partials: P,Q (one f per thread)
  {
    const float w = W1[t];
    const float wp = fmaxf(w, 0.f), wn = fminf(w, 0.f);
    const float4 A = *(const float4*)(W2 + t*8);
    const float4 Bv = *(const float4*)(W2 + t*8 + 4);
    float accP[8], accQ[8];
    accP[0]=wp*A.x;  accQ[0]=wn*A.x;   accP[1]=wp*A.y;  accQ[1]=wn*A.y;
    accP[2]=wp*A.z;  accQ[2]=wn*A.z;   accP[3]=wp*A.w;  accQ[3]=wn*A.w;
    accP[4]=wp*Bv.x; accQ[4]=wn*Bv.x;  accP[5]=wp*Bv.y; accQ[5]=wn*Bv.y;
    accP[6]=wp*Bv.z; accQ[6]=wn*Bv.z;  accP[7]=wp*Bv.w; accQ[7]=wn*Bv.w;
    #pragma unroll
    for (int g = 0; g < 8; ++g){
      float p = accP[g], q = accQ[g];
      #pragma unroll
      for (int off = 32; off; off >>= 1){ p += __shfl_xor(p, off); q += __shfl_xor(q, off); }
      if (ln == 0){ pqpart[wv][g] = p; pqpart[wv][8+g] = q; }
    }
  }
  __syncthreads();   // B1

  // ================= region B =================
  const uint rowm = (uint)(rowW[lane*2 + (h>>1)] >> ((h&1)*32));  // cols 32h..32h+31 of row `lane`
  uint colm = 0;                                                   // rows 32h..32h+31 of col `lane`
  {
    const int wsel = lane >> 6, bsel = lane & 63;
    #pragma unroll 8
    for (int k = 0; k < 32; ++k)
      colm |= (uint)((rowW[(32*h + k)*2 + wsel] >> bsel) & 1ull) << k;
  }
  if (t < 64){
    float mx = fmaxf(xs[t], xs[t+64]);
    float mn = fminf(xs[t], xs[t+64]);
    #pragma unroll
    for (int off = 32; off; off >>= 1){
      mx = fmaxf(mx, __shfl_xor(mx, off));
      mn = fminf(mn, __shfl_xor(mn, off));
    }
    if (t == 0){ sred[0] = mx; sred[1] = mn; }
  }
  if (t == 0){
    float c1v = 0.f, c2v = 0.f;
    #pragma unroll
    for (int wvi = 0; wvi < 8; ++wvi){ c1v += cpart[wvi][0]; c2v += cpart[wvi][1]; }
    cons[0] = c1v; cons[1] = c2v;
    float pAx=0.f, qAx=0.f, pBx=0.f, qBx=0.f;
    #pragma unroll
    for (int g = 0; g < 8; ++g){
      float P = 0.f, Q = 0.f;
      #pragma unroll
      for (int wvi = 0; wvi < 8; ++wvi){ P += pqpart[wvi][g]; Q += pqpart[wvi][8+g]; }
      cons[2+g] = P; cons[10+g] = Q;
      pAx = __fmaf_rn(P, a2reg[g],   pAx);  qAx = __fmaf_rn(Q, a2reg[g],   qAx);
      pBx = __fmaf_rn(P, a2reg[8+g], pBx);  qBx = __fmaf_rn(Q, a2reg[8+g], qBx);
    }
    cons[18]=pAx; cons[19]=qAx; cons[20]=pBx; cons[21]=qBx;
  }
  lstm8(0);
  __syncthreads();   // B2

  // ================= GAT1 factors =================
  float myE1=0.f, myEh=0.f, myA=0.f, myB=0.f, mythr=0.f, myx=0.f;
  {
    const float c1 = cons[0], c2 = cons[1];
    const float rmax = (c1 >= 0.f) ? c1*sred[0] : c1*sred[1];
    if (t < 128){
      myx = xs[t];
      float r  = c1*myx;
      float cj = c2*myx;
      float cb = lrelu(rmax + cj);
      myE1  = fexp(r - rmax);
      myEh  = fexp(0.5f*(r - rmax));
      myA   = fexp(rmax + cj - cb);
      myB   = fexp(0.5f*(rmax + cj) - cb);
      mythr = fexp(-cj - rmax);
      f2a[t] = make_float2(myE1, myEh);
      thr1[t] = mythr;
    }
  }
  lstm8(1);
  __syncthreads();   // B3

  // ---- GAT1 col pass (rows 32h..32h+31 of column `lane`) ----
  {
    const float thrj = thr1[lane];
    float s1 = 0.f, s2 = 0.f;
    #pragma unroll 8
    for (int k = 0; k < 32; ++k){
      float2 E = f2a[32*h + k];
      bool m = ((colm >> k) & 1u);
      bool cond = (E.x >= thrj);
      s1 += (m &&  cond) ? E.x : 0.f;
      s2 += (m && !cond) ? E.y : 0.f;
    }
    red4[h][lane] = make_float2(s1, s2);
  }
  lstm8(2);
  __syncthreads();   // B4

  if (t < 128){
    float sx = 0.f, sy = 0.f;
    #pragma unroll
    for (int g = 0; g < 4; ++g){ float2 v = red4[g][t]; sx += v.x; sy += v.y; }
    float den = __fmaf_rn(myA, sx, myB*sy);
    float cr = frcp(den);
    q4[t] = make_float4(myA*cr*myx, myB*cr*myx, mythr, 0.f);
  }
  lstm8(3);
  __syncthreads();   // B5

  // ---- GAT1 row pass (cols 32h..32h+31 of row `lane`) ----
  {
    const float2 Eo = f2a[lane];
    float t1 = 0.f, t2 = 0.f;
    #pragma unroll 8
    for (int k = 0; k < 32; ++k){
      float4 G = q4[32*h + k];
      bool m = ((rowm >> k) & 1u);
      bool cond = (Eo.x >= G.z);
      t1 += (m &&  cond) ? G.x : 0.f;
      t2 += (m && !cond) ? G.y : 0.f;
    }
    red4[h][lane] = make_float2(t1, t2);
  }
  lstm8(4);
  __syncthreads();   // B6

  float u = 0.f, eBv = 0.f, eAv = 0.f;
  if (t < 128){
    float sx = 0.f, sy = 0.f;
    #pragma unroll
    for (int g = 0; g < 4; ++g){ float2 v = red4[g][t]; sx += v.x; sy += v.y; }
    u = __fmaf_rn(myE1, sx, myEh*sy);
    eAv = (u >= 0.f ? cons[18] : cons[19])*u;
    eBv = (u >= 0.f ? cons[20] : cons[21])*u;
    eAs[t] = eAv;
  }
  lstm8(5);
  __syncthreads();   // B7

  if (t < 64){
    float mx = fmaxf(eAs[t], eAs[t+64]);
    #pragma unroll
    for (int off = 32; off; off >>= 1) mx = fmaxf(mx, __shfl_xor(mx, off));
    if (t == 0) sred[2] = mx;
  }
  lstm8(6);
  __syncthreads();   // B8

  // ================= GAT2 factors =================
  float myE1b=0.f, myEhb=0.f, myA2=0.f, myB2=0.f;
  {
    const float eAmax = sred[2];
    if (t < 128){
      float cb = lrelu(eAmax + eBv);
      myE1b = fexp(eAv - eAmax);
      myEhb = fexp(0.5f*(eAv - eAmax));
      myA2  = fexp(eAmax + eBv - cb);
      myB2  = fexp(0.5f*(eAmax + eBv) - cb);
      float th = fexp(-eBv - eAmax);
      f2a[t] = make_float2(myE1b, myEhb);
      thr1[t] = th;
    }
  }
  lstm8(7);          // LSTM complete
  __syncthreads();   // B9

  // ---- GAT2 col pass ----
  {
    const float thrj = thr1[lane];
    float s1 = 0.f, s2 = 0.f;
    #pragma unroll 8
    for (int k = 0; k < 32; ++k){
      float2 E = f2a[32*h + k];
      bool m = ((colm >> k) & 1u);
      bool cond = (E.x >= thrj);
      s1 += (m &&  cond) ? E.x : 0.f;
      s2 += (m && !cond) ? E.y : 0.f;
    }
    red4[h][lane] = make_float2(s1, s2);
  }
  __syncthreads();   // B10

  if (t < 128){
    float sx = 0.f, sy = 0.f;
    #pragma unroll
    for (int g = 0; g < 4; ++g){ float2 v = red4[g][t]; sx += v.x; sy += v.y; }
    float den = __fmaf_rn(myA2, sx, myB2*sy);
    float cr = frcp(den);
    float up = fmaxf(u, 0.f), un = fminf(u, 0.f);
    q4[t] = make_float4(myA2*cr*up, myB2*cr*up, myA2*cr*un, myB2*cr*un);
  }
  __syncthreads();   // B11

  // ---- GAT2 row pass ----
  {
    const float2 Eo = f2a[lane];
    float sp1=0.f, sp2=0.f, sn1=0.f, sn2=0.f;
    #pragma unroll 8
    for (int k = 0; k < 32; ++k){
      int j = 32*h + k;
      float4 G = q4[j];
      float thj = thr1[j];
      bool m = ((rowm >> k) & 1u);
      bool cond = (Eo.x >= thj);
      sp1 += (m &&  cond) ? G.x : 0.f;
      sp2 += (m && !cond) ? G.y : 0.f;
      sn1 += (m &&  cond) ? G.z : 0.f;
      sn2 += (m && !cond) ? G.w : 0.f;
    }
    pool4[h][lane] = make_float4(sp1, sp2, sn1, sn2);
  }
  __syncthreads();   // B12

  if (t < 128){
    float sx=0.f, sy=0.f, sz=0.f, sw=0.f;
    #pragma unroll
    for (int g = 0; g < 4; ++g){ float4 v = pool4[g][t]; sx+=v.x; sy+=v.y; sz+=v.z; sw+=v.w; }
    float sp = __fmaf_rn(myE1b, sx, myEhb*sy);
    float sn = __fmaf_rn(myE1b, sz, myEhb*sw);
    float acc = 0.f;
    #pragma unroll
    for (int g = 0; g < 8; ++g) acc += reluf(__fmaf_rn(sp, cons[2+g], sn*cons[10+g]));
    hm[t] = 0.125f*acc;
  }
  __syncthreads();   // B13

  // ---- attention pooling (rows 32h..32h+31) ----
  {
    const int n = lane;
    float a0=0.f, a1v=0.f, v0=0.f, v1=0.f;
    const int m0 = h*32;
    #pragma unroll 4
    for (int k = 0; k < 32; ++k){
      int m = m0 + k;
      float hmv = hm[m], tv = tim[m];
      float wg = Weight[(m<<7) + n], wvv = Wv[(m<<7) + n];
      a0 = __fmaf_rn(hmv, wg, a0); a1v = __fmaf_rn(tv, wg, a1v);
      v0 = __fmaf_rn(hmv, wvv, v0); v1 = __fmaf_rn(tv, wvv, v1);
    }
    pool4[h][n] = make_float4(a0, a1v, v0, v1);
  }
  __syncthreads();   // B14

  float att0 = 0.f, att1 = 0.f, rsv = 0.f;
  if (t < 128){
    float A0=0.f, A1=0.f, V0=0.f, V1=0.f;
    #pragma unroll
    for (int g = 0; g < 4; ++g){ float4 v = pool4[g][t]; A0+=v.x; A1+=v.y; V0+=v.z; V1+=v.w; }
    red4[0][t] = make_float2(V0, V1);
    float mx = fmaxf(A0, A1);
    att0 = fexp(A0 - mx); att1 = fexp(A1 - mx);
    rsv = frcp(att0 + att1);
  }
  __syncthreads();   // B15

  if (t < 128){
    float r0, r1;
    if (t < 64){ r0 = red4[0][2*t].x;     r1 = red4[0][2*t+1].x; }
    else       { r0 = red4[0][2*t-128].y; r1 = red4[0][2*t-127].y; }
    hq[t] = (reluf(r0)*att0 + reluf(r1)*att1)*rsv;
  }
  if (t >= 192 && t < 256) hq[128 + (t - 192)] = ips[t - 192];
  __syncthreads();   // B16

  // ---- MHA ----
  const float wq = mha_in_w[0], wk = mha_in_w[1], wvv_ = mha_in_w[2];
  const float bq = mha_in_b[0], bk = mha_in_b[1], bv = mha_in_b[2];
  const float wo = mha_out_w[0], bo = mha_out_b[0];
  if (t < 192){
    float hv_ = hq[t];
    kv[t] = make_float2(__fmaf_rn(hv_, wk, bk), __fmaf_rn(hv_, wvv_, bv));
  }
  __syncthreads();   // B17

  if (t < 64){
    float k0 = kv[t].x, k1 = kv[t+64].x, k2 = kv[t+128].x;
    float mx = fmaxf(fmaxf(k0, k1), k2);
    float mn = fminf(fminf(k0, k1), k2);
    #pragma unroll
    for (int off = 32; off; off >>= 1){
      mx = fmaxf(mx, __shfl_xor(mx, off));
      mn = fminf(mn, __shfl_xor(mn, off));
    }
    if (t == 0){ sred[3] = mx; sred[4] = mn; }
  }
  __syncthreads();   // B18

  if (t < 384){
    const int half = (t >= 192), tt = t - half*192;
    float qi = __fmaf_rn(hq[tt], wq, bq);
    float mx = (qi >= 0.f) ? qi*sred[3] : qi*sred[4];
    const float qi2 = qi*L2E, mx2 = mx*L2E;
    float den = 0.f, num = 0.f;
    const int j0 = half*96;
    #pragma unroll 8
    for (int jj = 0; jj < 96; ++jj){
      float2 K = kv[j0 + jj];
      float e = __builtin_amdgcn_exp2f(__fmaf_rn(qi2, K.x, -mx2));
      den += e; num = __fmaf_rn(e, K.y, num);
    }
    pden[half][tt] = den; pnum[half][tt] = num;
  }
  __syncthreads();   // B19

  if (t < 192){
    float den = pden[0][t] + pden[1][t];
    float num = pnum[0][t] + pnum[1][t];
    h2s[t] = __fmaf_rn(num*frcp(den), wo, bo) + hq[t];
  }
  __syncthreads();   // B20

  // ---- fl1: 192->128 (4-way split over j) ----
  {
    const int n = t & 127, qtr = t >> 7;
    float acc = 0.f;
    const int i0 = qtr*48;
    #pragma unroll 8
    for (int k = 0; k < 48; ++k){
      int i = i0 + k;
      acc = __fmaf_rn(h2s[i], fl1_w[i*128 + n], acc);
    }
    red4[qtr][n].x = acc;
  }
  __syncthreads();   // B21

  if (t < 128) thr1[t] = reluf(red4[0][t].x + red4[1][t].x + red4[2][t].x + red4[3][t].x + fl1_b[t]);
  __syncthreads();   // B22

  // ---- fl2: 128->32 (4-way split) ----
  if (t < 128){
    const int n = t & 31, seg = t >> 5;
    float p = 0.f;
    #pragma unroll 8
    for (int k = 0; k < 32; ++k){
      int i = seg*32 + k;
      p = __fmaf_rn(thr1[i], fl2_w[i*32 + n], p);
    }
    eAs[t] = p;
  }
  __syncthreads();   // B23

  if (t < 32) hm[t] = tanh_n(eAs[t] + eAs[t+32] + eAs[t+64] + eAs[t+96] + fl2_b[t]);
  __syncthreads();   // B24

  // ---- fl3: 32->1 ----
  if (t < 64){
    float p = (t < 32) ? hm[t]*fl3_w[t] : 0.f;
    #pragma unroll
    for (int off = 32; off; off >>= 1) p += __shfl_xor(p, off);
    if (t == 0) out[b] = reluf(p + fl3_b[0]);
  }
}

extern "C" void kernel_launch(void* const* d_in, const int* in_sizes, int n_in,
                              void* d_out, int out_size, void* d_ws, size_t ws_size,
                              hipStream_t stream) {
  const int*   adj    = (const int*)  d_in[0];
  const float* feat   = (const float*)d_in[1];
  const float* timei  = (const float*)d_in[2];
  const float* ipop   = (const float*)d_in[3];
  const float* W1     = (const float*)d_in[4];
  const float* a1     = (const float*)d_in[5];
  const float* W2     = (const float*)d_in[6];
  const float* a2     = (const float*)d_in[7];
  const float* Weight = (const float*)d_in[8];
  const float* Wv     = (const float*)d_in[9];
  const float* wih0   = (const float*)d_in[10];
  const float* whh0   = (const float*)d_in[11];
  const float* bih0   = (const float*)d_in[12];
  const float* bhh0   = (const float*)d_in[13];
  const float* wih1   = (const float*)d_in[14];
  const float* whh1   = (const float*)d_in[15];
  const float* bih1   = (const float*)d_in[16];
  const float* bhh1   = (const float*)d_in[17];
  const float* mha_in_w  = (const float*)d_in[18];
  const float* mha_in_b  = (const float*)d_in[19];
  const float* mha_out_w = (const float*)d_in[20];
  const float* mha_out_b = (const float*)d_in[21];
  const float* fl1_w = (const float*)d_in[22];
  const float* fl1_b = (const float*)d_in[23];
  const float* fl2_w = (const float*)d_in[24];
  const float* fl2_b = (const float*)d_in[25];
  const float* fl3_w = (const float*)d_in[26];
  const float* fl3_b = (const float*)d_in[27];

  fused_kernel<<<512, 512, 0, stream>>>(adj, feat, timei, Weight, Wv,
                                        W1, a1, W2, a2, ipop,
                                        wih0, whh0, bih0, bhh0,
                                        wih1, whh1, bih1, bhh1,
                                        mha_in_w, mha_in_b, mha_out_w, mha_out_b,
                                        fl1_w, fl1_b, fl2_w, fl2_b, fl3_w, fl3_b,
                                        (float*)d_out);
}

// Round 11
// 42.822 us; speedup vs baseline: 1.7606x; 1.0252x over previous
//
#include <hip/hip_runtime.h>
#include <math.h>

typedef unsigned int uint;
typedef unsigned long long ull;

#define L2E 1.44269504f

__device__ __forceinline__ float lrelu(float z){ return fmaxf(z, 0.5f*z); }
__device__ __forceinline__ float reluf(float z){ return fmaxf(z, 0.f); }
__device__ __forceinline__ float fexp(float z){ return __builtin_amdgcn_exp2f(z*L2E); }
__device__ __forceinline__ float frcp(float z){ return __builtin_amdgcn_rcpf(z); }
__device__ __forceinline__ float tanh_n(float z){
  return __fmaf_rn(2.f, __builtin_amdgcn_rcpf(1.f + __builtin_amdgcn_exp2f(-2.f*L2E*z)), -1.f);
}

// ===== ONE kernel, 512 blocks x 512 threads; GAT softmax via max-identity (branch-free) =====
__global__ __launch_bounds__(512) void fused_kernel(
    const int* __restrict__ adj, const float* __restrict__ feat,
    const float* __restrict__ timei,
    const float* __restrict__ Weight, const float* __restrict__ Wv,
    const float* __restrict__ W1, const float* __restrict__ a1,
    const float* __restrict__ W2, const float* __restrict__ a2,
    const float* __restrict__ ipop,
    const float* __restrict__ wih0, const float* __restrict__ whh0,
    const float* __restrict__ bih0, const float* __restrict__ bhh0,
    const float* __restrict__ wih1, const float* __restrict__ whh1,
    const float* __restrict__ bih1, const float* __restrict__ bhh1,
    const float* __restrict__ mha_in_w, const float* __restrict__ mha_in_b,
    const float* __restrict__ mha_out_w, const float* __restrict__ mha_out_b,
    const float* __restrict__ fl1_w, const float* __restrict__ fl1_b,
    const float* __restrict__ fl2_w, const float* __restrict__ fl2_b,
    const float* __restrict__ fl3_w, const float* __restrict__ fl3_b,
    float* __restrict__ out)
{
  const int b = blockIdx.x, t = threadIdx.x;
  const int lane = t & 127, h = t >> 7;        // h in {0,1,2,3}
  const int wv = t >> 6, ln = t & 63;

  __shared__ ull   rowW[256];
  __shared__ float xs[128], tim[128], hm[128], eAs[128], rho_s[128];
  __shared__ float2 f2a[128];                  // {E1_i, Eh_i}
  __shared__ float  red1[4][128];              // scalar pass partials
  __shared__ float2 red4[4][128];              // GAT2-row / pooling-V / fl1 partials
  __shared__ float4 q4[128];
  __shared__ float4 pool4[4][128];
  __shared__ float2 kv[192];
  __shared__ float  hq[192], h2s[192];
  __shared__ float  pden[2][192], pnum[2][192];
  __shared__ float  sred[8];
  __shared__ float  cpart[8][2];
  __shared__ float  pqpart[8][16];
  __shared__ float  cons[24];
  __shared__ float  ips[64];

  // ================= region A (pre-B1) =================
  if (t < 128){ xs[t] = feat[b*128 + t]; tim[t] = timei[b*128 + t]; }

  float a2reg[16];
  if (t == 0){
    #pragma unroll
    for (int g = 0; g < 16; ++g) a2reg[g] = a2[g];
  }

  // LSTM prologue (thread 511 only)
  float h1v=0.f, c1s=0.f, h2v=0.f, c2s=0.f;
  float wi0s[4], wh0s[4], bb0s[4], wi1s[4], wh1s[4], bb1s[4];
  const float4* xsrc4 = (const float4*)(ipop + b*64);
  float4 xcur0, xcur1;
  if (t == 511){
    #pragma unroll
    for (int k = 0; k < 4; ++k){
      const float s = (k == 2) ? -2.f*L2E : -L2E;
      wi0s[k]=wih0[k]*s; wh0s[k]=whh0[k]*s; bb0s[k]=(bih0[k]+bhh0[k])*s;
      wi1s[k]=wih1[k]*s; wh1s[k]=whh1[k]*s; bb1s[k]=(bih1[k]+bhh1[k])*s;
    }
    xcur0 = xsrc4[0]; xcur1 = xsrc4[1];
  }
  auto lstm8 = [&](int c){
    if (t != 511) return;
    const float4 xa = xcur0, xb = xcur1;
    if (c < 7){ xcur0 = xsrc4[2*c+2]; xcur1 = xsrc4[2*c+3]; }
    float o[8];
    #pragma unroll
    for (int si = 0; si < 8; ++si){
      const float x = (si==0)?xa.x:(si==1)?xa.y:(si==2)?xa.z:(si==3)?xa.w:
                      (si==4)?xb.x:(si==5)?xb.y:(si==6)?xb.z:xb.w;
      float gi = frcp(1.f + __builtin_amdgcn_exp2f(__fmaf_rn(x, wi0s[0], __fmaf_rn(h1v, wh0s[0], bb0s[0]))));
      float gf = frcp(1.f + __builtin_amdgcn_exp2f(__fmaf_rn(x, wi0s[1], __fmaf_rn(h1v, wh0s[1], bb0s[1]))));
      float gg = __fmaf_rn(2.f, frcp(1.f + __builtin_amdgcn_exp2f(__fmaf_rn(x, wi0s[2], __fmaf_rn(h1v, wh0s[2], bb0s[2])))), -1.f);
      float go = frcp(1.f + __builtin_amdgcn_exp2f(__fmaf_rn(x, wi0s[3], __fmaf_rn(h1v, wh0s[3], bb0s[3]))));
      c1s = gf*c1s + gi*gg;  h1v = go*tanh_n(c1s);
      float hi = frcp(1.f + __builtin_amdgcn_exp2f(__fmaf_rn(h1v, wi1s[0], __fmaf_rn(h2v, wh1s[0], bb1s[0]))));
      float hf = frcp(1.f + __builtin_amdgcn_exp2f(__fmaf_rn(h1v, wi1s[1], __fmaf_rn(h2v, wh1s[1], bb1s[1]))));
      float hg = __fmaf_rn(2.f, frcp(1.f + __builtin_amdgcn_exp2f(__fmaf_rn(h1v, wi1s[2], __fmaf_rn(h2v, wh1s[2], bb1s[2])))), -1.f);
      float ho = frcp(1.f + __builtin_amdgcn_exp2f(__fmaf_rn(h1v, wi1s[3], __fmaf_rn(h2v, wh1s[3], bb1s[3])))) ;
      c2s = hf*c2s + hi*hg;  h2v = ho*tanh_n(c2s);
      o[si] = h2v;
    }
    #pragma unroll
    for (int si = 0; si < 8; ++si) ips[8*c + si] = o[si];
  };

  // ballot pack
  {
    const int* abase = adj + (((long)b) << 14) + wv*2048 + ln;
    ull myword = 0;
    #pragma unroll
    for (int blk = 0; blk < 4; ++blk){
      int v[8];
      #pragma unroll
      for (int q = 0; q < 8; ++q) v[q] = abase[(blk*8 + q)*64];
      #pragma unroll
      for (int q = 0; q < 8; ++q){
        ull m = __ballot(v[q] > 0);
        myword = (ln == blk*8 + q) ? m : myword;
      }
    }
    if (ln < 32) rowW[wv*32 + ln] = myword;
  }

  // consts partials
  {
    float w0 = W1[t];
    float s1 = w0*a1[t];
    float s2 = w0*a1[512+t];
    #pragma unroll
    for (int off = 32; off; off >>= 1){ s1 += __shfl_xor(s1, off); s2 += __shfl_xor(s2, off); }
    if (ln == 0){ cpart[wv][0] = s1; cpart[wv][1] = s2; }
  }
  {
    const float w = W1[t];
    const float wp = fmaxf(w, 0.f), wn = fminf(w, 0.f);
    const float4 A = *(const float4*)(W2 + t*8);
    const float4 Bv = *(const float4*)(W2 + t*8 + 4);
    float accP[8], accQ[8];
    accP[0]=wp*A.x;  accQ[0]=wn*A.x;   accP[1]=wp*A.y;  accQ[1]=wn*A.y;
    accP[2]=wp*A.z;  accQ[2]=wn*A.z;   accP[3]=wp*A.w;  accQ[3]=wn*A.w;
    accP[4]=wp*Bv.x; accQ[4]=wn*Bv.x;  accP[5]=wp*Bv.y; accQ[5]=wn*Bv.y;
    accP[6]=wp*Bv.z; accQ[6]=wn*Bv.z;  accP[7]=wp*Bv.w; accQ[7]=wn*Bv.w;
    #pragma unroll
    for (int g = 0; g < 8; ++g){
      float p = accP[g], q = accQ[g];
      #pragma unroll
      for (int off = 32; off; off >>= 1){ p += __shfl_xor(p, off); q += __shfl_xor(q, off); }
      if (ln == 0){ pqpart[wv][g] = p; pqpart[wv][8+g] = q; }
    }
  }
  __syncthreads();   // B1

  // ================= region B =================
  const uint rowm = (uint)(rowW[lane*2 + (h>>1)] >> ((h&1)*32));
  uint colm = 0;
  {
    const int wsel = lane >> 6, bsel = lane & 63;
    #pragma unroll 8
    for (int k = 0; k < 32; ++k)
      colm |= (uint)((rowW[(32*h + k)*2 + wsel] >> bsel) & 1ull) << k;
  }
  if (t < 64){
    float mx = fmaxf(xs[t], xs[t+64]);
    float mn = fminf(xs[t], xs[t+64]);
    #pragma unroll
    for (int off = 32; off; off >>= 1){
      mx = fmaxf(mx, __shfl_xor(mx, off));
      mn = fminf(mn, __shfl_xor(mn, off));
    }
    if (t == 0){ sred[0] = mx; sred[1] = mn; }
  }
  if (t == 0){
    float c1v = 0.f, c2v = 0.f;
    #pragma unroll
    for (int wvi = 0; wvi < 8; ++wvi){ c1v += cpart[wvi][0]; c2v += cpart[wvi][1]; }
    cons[0] = c1v; cons[1] = c2v;
    float pAx=0.f, qAx=0.f, pBx=0.f, qBx=0.f;
    #pragma unroll
    for (int g = 0; g < 8; ++g){
      float P = 0.f, Q = 0.f;
      #pragma unroll
      for (int wvi = 0; wvi < 8; ++wvi){ P += pqpart[wvi][g]; Q += pqpart[wvi][8+g]; }
      cons[2+g] = P; cons[10+g] = Q;
      pAx = __fmaf_rn(P, a2reg[g],   pAx);  qAx = __fmaf_rn(Q, a2reg[g],   qAx);
      pBx = __fmaf_rn(P, a2reg[8+g], pBx);  qBx = __fmaf_rn(Q, a2reg[8+g], qBx);
    }
    cons[18]=pAx; cons[19]=qAx; cons[20]=pBx; cons[21]=qBx;
  }
  lstm8(0);
  __syncthreads();   // B2

  // ====== GAT1 factors: att_ij = max(E1_i, rho_j*Eh_i)/s_j (A_j cancels) ======
  float myE1=0.f, myRho=0.f, myx=0.f;
  {
    const float c1 = cons[0], c2 = cons[1];
    const float rmax = (c1 >= 0.f) ? c1*sred[0] : c1*sred[1];
    if (t < 128){
      myx = xs[t];
      float r  = c1*myx;
      float cj = c2*myx;
      float d  = r - rmax;
      myE1 = fexp(d);
      float Eh = fexp(0.5f*d);
      myRho = fexp(-0.5f*fmaxf(rmax + cj, -170.f));   // clamp: overflow guard only
      f2a[t] = make_float2(myE1, Eh);
      rho_s[t] = myRho;
    }
  }
  lstm8(1);
  __syncthreads();   // B3

  // ---- GAT1 col pass: s_j = sum_i m*max(E1_i, rho_j*Eh_i) ----
  {
    const float rho = rho_s[lane];
    float s = 0.f;
    #pragma unroll 8
    for (int k = 0; k < 32; ++k){
      float2 E = f2a[32*h + k];
      float v = fmaxf(E.x, rho*E.y);
      s += ((colm >> k) & 1u) ? v : 0.f;
    }
    red1[h][lane] = s;
  }
  lstm8(2);
  __syncthreads();   // B4

  if (t < 128){
    float s = red1[0][t] + red1[1][t] + red1[2][t] + red1[3][t];
    float sinv = frcp(s);
    float ax = fabsf(myx)*sinv;
    q4[t] = make_float4(ax, myRho*ax, (myx >= 0.f) ? 1.f : -1.f, 0.f);
  }
  lstm8(3);
  __syncthreads();   // B5

  // ---- GAT1 row pass: u_i = E1_i * sum_j m*sgn_j*max(G1_j, om_i*G2_j) ----
  {
    const float om = frcp(f2a[lane].y);     // om_i = Eh/E1 = 1/Eh
    float acc = 0.f;
    #pragma unroll 8
    for (int k = 0; k < 32; ++k){
      float4 G = q4[32*h + k];
      float v = fmaxf(G.x, om*G.y);
      float sg = ((rowm >> k) & 1u) ? G.z : 0.f;
      acc = __fmaf_rn(v, sg, acc);
    }
    red1[h][lane] = acc;
  }
  lstm8(4);
  __syncthreads();   // B6

  float u = 0.f, eBv = 0.f, eAv = 0.f;
  if (t < 128){
    u = myE1*(red1[0][t] + red1[1][t] + red1[2][t] + red1[3][t]);
    eAv = (u >= 0.f ? cons[18] : cons[19])*u;
    eBv = (u >= 0.f ? cons[20] : cons[21])*u;
    eAs[t] = eAv;
  }
  lstm8(5);
  __syncthreads();   // B7

  if (t < 64){
    float mx = fmaxf(eAs[t], eAs[t+64]);
    #pragma unroll
    for (int off = 32; off; off >>= 1) mx = fmaxf(mx, __shfl_xor(mx, off));
    if (t == 0) sred[2] = mx;
  }
  lstm8(6);
  __syncthreads();   // B8

  // ====== GAT2 factors ======
  float myE1b=0.f;
  {
    const float eAmax = sred[2];
    if (t < 128){
      float d2 = eAv - eAmax;
      myE1b = fexp(d2);
      float Ehb = fexp(0.5f*d2);
      float rho2 = fexp(-0.5f*fmaxf(eAmax + eBv, -170.f));
      f2a[t] = make_float2(myE1b, Ehb);
      rho_s[t] = rho2;
    }
  }
  lstm8(7);
  __syncthreads();   // B9

  // ---- GAT2 col pass ----
  {
    const float rho = rho_s[lane];
    float s = 0.f;
    #pragma unroll 8
    for (int k = 0; k < 32; ++k){
      float2 E = f2a[32*h + k];
      float v = fmaxf(E.x, rho*E.y);
      s += ((colm >> k) & 1u) ? v : 0.f;
    }
    red1[h][lane] = s;
  }
  __syncthreads();   // B10

  if (t < 128){
    float s = red1[0][t] + red1[1][t] + red1[2][t] + red1[3][t];
    float sinv = frcp(s);
    float rho2 = rho_s[t];
    float up = fmaxf(u, 0.f)*sinv, un = -fminf(u, 0.f)*sinv;
    q4[t] = make_float4(up, rho2*up, un, rho2*un);
  }
  __syncthreads();   // B11

  // ---- GAT2 row pass: sp = E1b*accp, sn = -E1b*accn ----
  {
    const float om = frcp(f2a[lane].y);
    float accp = 0.f, accn = 0.f;
    #pragma unroll 8
    for (int k = 0; k < 32; ++k){
      float4 G = q4[32*h + k];
      bool m = ((rowm >> k) & 1u);
      float v1 = fmaxf(G.x, om*G.y);
      float v2 = fmaxf(G.z, om*G.w);
      accp += m ? v1 : 0.f;
      accn += m ? v2 : 0.f;
    }
    red4[h][lane] = make_float2(accp, accn);
  }
  __syncthreads();   // B12

  if (t < 128){
    float ap=0.f, an=0.f;
    #pragma unroll
    for (int g = 0; g < 4; ++g){ float2 v = red4[g][t]; ap += v.x; an += v.y; }
    float sp = myE1b*ap, sn = -myE1b*an;
    float acc = 0.f;
    #pragma unroll
    for (int g = 0; g < 8; ++g) acc += reluf(__fmaf_rn(sp, cons[2+g], sn*cons[10+g]));
    hm[t] = 0.125f*acc;
  }
  __syncthreads();   // B13

  // ---- attention pooling ----
  {
    const int n = lane;
    float a0=0.f, a1v=0.f, v0=0.f, v1=0.f;
    const int m0 = h*32;
    #pragma unroll 4
    for (int k = 0; k < 32; ++k){
      int m = m0 + k;
      float hmv = hm[m], tv = tim[m];
      float wg = Weight[(m<<7) + n], wvv = Wv[(m<<7) + n];
      a0 = __fmaf_rn(hmv, wg, a0); a1v = __fmaf_rn(tv, wg, a1v);
      v0 = __fmaf_rn(hmv, wvv, v0); v1 = __fmaf_rn(tv, wvv, v1);
    }
    pool4[h][n] = make_float4(a0, a1v, v0, v1);
  }
  __syncthreads();   // B14

  float att0 = 0.f, att1 = 0.f, rsv = 0.f;
  if (t < 128){
    float A0=0.f, A1=0.f, V0=0.f, V1=0.f;
    #pragma unroll
    for (int g = 0; g < 4; ++g){ float4 v = pool4[g][t]; A0+=v.x; A1+=v.y; V0+=v.z; V1+=v.w; }
    red4[0][t] = make_float2(V0, V1);
    float mx = fmaxf(A0, A1);
    att0 = fexp(A0 - mx); att1 = fexp(A1 - mx);
    rsv = frcp(att0 + att1);
  }
  __syncthreads();   // B15

  if (t < 128){
    float r0, r1;
    if (t < 64){ r0 = red4[0][2*t].x;     r1 = red4[0][2*t+1].x; }
    else       { r0 = red4[0][2*t-128].y; r1 = red4[0][2*t-127].y; }
    hq[t] = (reluf(r0)*att0 + reluf(r1)*att1)*rsv;
  }
  if (t >= 192 && t < 256) hq[128 + (t - 192)] = ips[t - 192];
  __syncthreads();   // B16

  // ---- MHA ----
  const float wq = mha_in_w[0], wk = mha_in_w[1], wvv_ = mha_in_w[2];
  const float bq = mha_in_b[0], bk = mha_in_b[1], bv = mha_in_b[2];
  const float wo = mha_out_w[0], bo = mha_out_b[0];
  if (t < 192){
    float hv_ = hq[t];
    kv[t] = make_float2(__fmaf_rn(hv_, wk, bk), __fmaf_rn(hv_, wvv_, bv));
  }
  __syncthreads();   // B17

  if (t < 64){
    float k0 = kv[t].x, k1 = kv[t+64].x, k2 = kv[t+128].x;
    float mx = fmaxf(fmaxf(k0, k1), k2);
    float mn = fminf(fminf(k0, k1), k2);
    #pragma unroll
    for (int off = 32; off; off >>= 1){
      mx = fmaxf(mx, __shfl_xor(mx, off));
      mn = fminf(mn, __shfl_xor(mn, off));
    }
    if (t == 0){ sred[3] = mx; sred[4] = mn; }
  }
  __syncthreads();   // B18

  if (t < 384){
    const int half = (t >= 192), tt = t - half*192;
    float qi = __fmaf_rn(hq[tt], wq, bq);
    float mx = (qi >= 0.f) ? qi*sred[3] : qi*sred[4];
    const float qi2 = qi*L2E, mx2 = mx*L2E;
    float den = 0.f, num = 0.f;
    const int j0 = half*96;
    #pragma unroll 8
    for (int jj = 0; jj < 96; ++jj){
      float2 K = kv[j0 + jj];
      float e = __builtin_amdgcn_exp2f(__fmaf_rn(qi2, K.x, -mx2));
      den += e; num = __fmaf_rn(e, K.y, num);
    }
    pden[half][tt] = den; pnum[half][tt] = num;
  }
  __syncthreads();   // B19

  if (t < 192){
    float den = pden[0][t] + pden[1][t];
    float num = pnum[0][t] + pnum[1][t];
    h2s[t] = __fmaf_rn(num*frcp(den), wo, bo) + hq[t];
  }
  __syncthreads();   // B20

  // ---- fl1: 192->128 (4-way split) ----
  {
    const int n = t & 127, qtr = t >> 7;
    float acc = 0.f;
    const int i0 = qtr*48;
    #pragma unroll 8
    for (int k = 0; k < 48; ++k){
      int i = i0 + k;
      acc = __fmaf_rn(h2s[i], fl1_w[i*128 + n], acc);
    }
    red4[qtr][n].x = acc;
  }
  __syncthreads();   // B21

  if (t < 128) rho_s[t] = reluf(red4[0][t].x + red4[1][t].x + red4[2][t].x + red4[3][t].x + fl1_b[t]);
  __syncthreads();   // B22

  // ---- fl2: 128->32 (4-way split) ----
  if (t < 128){
    const int n = t & 31, seg = t >> 5;
    float p = 0.f;
    #pragma unroll 8
    for (int k = 0; k < 32; ++k){
      int i = seg*32 + k;
      p = __fmaf_rn(rho_s[i], fl2_w[i*32 + n], p);
    }
    eAs[t] = p;
  }
  __syncthreads();   // B23

  if (t < 32) hm[t] = tanh_n(eAs[t] + eAs[t+32] + eAs[t+64] + eAs[t+96] + fl2_b[t]);
  __syncthreads();   // B24

  // ---- fl3: 32->1 ----
  if (t < 64){
    float p = (t < 32) ? hm[t]*fl3_w[t] : 0.f;
    #pragma unroll
    for (int off = 32; off; off >>= 1) p += __shfl_xor(p, off);
    if (t == 0) out[b] = reluf(p + fl3_b[0]);
  }
}

extern "C" void kernel_launch(void* const* d_in, const int* in_sizes, int n_in,
                              void* d_out, int out_size, void* d_ws, size_t ws_size,
                              hipStream_t stream) {
  const int*   adj    = (const int*)  d_in[0];
  const float* feat   = (const float*)d_in[1];
  const float* timei  = (const float*)d_in[2];
  const float* ipop   = (const float*)d_in[3];
  const float* W1     = (const float*)d_in[4];
  const float* a1     = (const float*)d_in[5];
  const float* W2     = (const float*)d_in[6];
  const float* a2     = (const float*)d_in[7];
  const float* Weight = (const float*)d_in[8];
  const float* Wv     = (const float*)d_in[9];
  const float* wih0   = (const float*)d_in[10];
  const float* whh0   = (const float*)d_in[11];
  const float* bih0   = (const float*)d_in[12];
  const float* bhh0   = (const float*)d_in[13];
  const float* wih1   = (const float*)d_in[14];
  const float* whh1   = (const float*)d_in[15];
  const float* bih1   = (const float*)d_in[16];
  const float* bhh1   = (const float*)d_in[17];
  const float* mha_in_w  = (const float*)d_in[18];
  const float* mha_in_b  = (const float*)d_in[19];
  const float* mha_out_w = (const float*)d_in[20];
  const float* mha_out_b = (const float*)d_in[21];
  const float* fl1_w = (const float*)d_in[22];
  const float* fl1_b = (const float*)d_in[23];
  const float* fl2_w = (const float*)d_in[24];
  const float* fl2_b = (const float*)d_in[25];
  const float* fl3_w = (const float*)d_in[26];
  const float* fl3_b = (const float*)d_in[27];

  fused_kernel<<<512, 512, 0, stream>>>(adj, feat, timei, Weight, Wv,
                                        W1, a1, W2, a2, ipop,
                                        wih0, whh0, bih0, bhh0,
                                        wih1, whh1, bih1, bhh1,
                                        mha_in_w, mha_in_b, mha_out_w, mha_out_b,
                                        fl1_w, fl1_b, fl2_w, fl2_b, fl3_w, fl3_b,
                                        (float*)d_out);
}